// Round 4
// baseline (2059.361 us; speedup 1.0000x reference)
//
#include <hip/hip_runtime.h>
#include <hip/hip_bf16.h>

#define DD   128
#define HH   8

__device__ __forceinline__ float b2f(unsigned short v){
  union { unsigned int u; float f; } x; x.u = ((unsigned int)v) << 16; return x.f;
}
__device__ __forceinline__ unsigned short f2b(float f){
  __hip_bfloat16 h = __float2bfloat16(f);
  return *(unsigned short*)&h;
}
struct __align__(8) us4 { unsigned short x,y,z,w; };

__device__ __forceinline__ float gld(const void* p, size_t i, bool f32){
  if (f32) return ((const float*)p)[i];
  return b2f(((const unsigned short*)p)[i]);
}

// Detect input float dtype. emb ~ N(0,1)*0.05. If f32, odd ushorts are mantissa
// garbage -> huge "bf16" values. flag=1 -> inputs are f32.
__global__ __launch_bounds__(64) void k_detect(const unsigned short* __restrict__ emb,
                                               int* __restrict__ flag){
  int t = threadIdx.x;
  float m = 0.f;
  for (int i=t; i<128; i+=64){
    float x = fabsf(b2f(emb[i]));
    if (x < 1e30f) m = fmaxf(m, x);
  }
#pragma unroll
  for (int s=1;s<64;s<<=1) m = fmaxf(m, __shfl_xor(m, s, 64));
  if (t==0) *flag = (m > 1e4f) ? 1 : 0;
}

// stage[i] = bf16( W[bo+i] ), dtype per flag. One 128x128 block per launch.
__global__ __launch_bounds__(256) void w_repack(
    const void* __restrict__ W, unsigned short* __restrict__ stage,
    size_t bo, const int* __restrict__ dflag)
{
  const bool wf32 = (*dflag) != 0;
  int i = blockIdx.x*256 + threadIdx.x;
  if (i >= DD*DD) return;
  float x;
  if (wf32) x = ((const float*)W)[bo + i];
  else      x = b2f(((const unsigned short*)W)[bo + i]);
  stage[i] = f2b(x);
}

enum { EPI_STORE=0, EPI_SCALE_CONST=1, EPI_SCALE_GATHER=2, EPI_RELU=3, EPI_RELU_RES=4 };

// C[M,128] = epi( prologue(A)[M,128] @ B[128,128] ), B bf16 staged.
// A: f32 (INB=0) or bf16 (INB=1). C: f32 (OUTB=0) or bf16 (OUTB=1).
// NORM (INB=0): A[m,c] /= (z[m,c>>4]+1e-9). EPI_RELU_RES: Rb bf16 residual.
template<int EPI, bool NORM, bool INB, bool OUTB>
__global__ __launch_bounds__(256) void gemm128(
    const void* __restrict__ Av, const unsigned short* __restrict__ B,
    void* __restrict__ Cv, int M,
    const float* __restrict__ z, const float* __restrict__ svec,
    const float* __restrict__ P2, const int* __restrict__ gidx,
    const unsigned short* __restrict__ Rb)
{
  __shared__ float As[32][68];
  __shared__ float Bs[32][128];
  const int tid = threadIdx.x;
  const int tx = tid & 31, ty = tid >> 5;
  const int row0 = blockIdx.x * 64;
  float acc[8][4];
#pragma unroll
  for (int i=0;i<8;i++){ acc[i][0]=0.f; acc[i][1]=0.f; acc[i][2]=0.f; acc[i][3]=0.f; }
  const int ar = tid >> 3, ac = (tid & 7) * 4;

  for (int k0=0;k0<128;k0+=32){
#pragma unroll
    for (int i=0;i<2;i++){
      int r = ar + i*32;
      int gr = row0 + r;
      float4 val = make_float4(0.f,0.f,0.f,0.f);
      if (gr < M){
        if (INB){
          us4 raw = *(const us4*)((const unsigned short*)Av + (size_t)gr*DD + k0 + ac);
          val = make_float4(b2f(raw.x), b2f(raw.y), b2f(raw.z), b2f(raw.w));
        } else {
          val = *(const float4*)((const float*)Av + (size_t)gr*DD + k0 + ac);
          if (NORM){
            float s = 1.0f / (z[(size_t)gr*HH + ((k0+ac)>>4)] + 1e-9f);
            val.x*=s; val.y*=s; val.z*=s; val.w*=s;
          }
        }
      }
      As[ac+0][r]=val.x; As[ac+1][r]=val.y; As[ac+2][r]=val.z; As[ac+3][r]=val.w;
    }
#pragma unroll
    for (int i=0;i<2;i++){
      int idx = tid + i*256;
      int l = idx * 8;
      int kr = l >> 7, c = l & 127;
      uint4 raw = *(const uint4*)(B + (size_t)(k0+kr)*DD + c);
      const unsigned short* hw = (const unsigned short*)&raw;
#pragma unroll
      for (int j=0;j<8;j++) Bs[kr][c+j] = b2f(hw[j]);
    }
    __syncthreads();
#pragma unroll
    for (int kk=0;kk<32;kk++){
      float4 a0 = *(const float4*)&As[kk][ty*8];
      float4 a1 = *(const float4*)&As[kk][ty*8+4];
      float4 b  = *(const float4*)&Bs[kk][tx*4];
      float av[8] = {a0.x,a0.y,a0.z,a0.w,a1.x,a1.y,a1.z,a1.w};
#pragma unroll
      for (int i=0;i<8;i++){
        acc[i][0] += av[i]*b.x; acc[i][1] += av[i]*b.y;
        acc[i][2] += av[i]*b.z; acc[i][3] += av[i]*b.w;
      }
    }
    __syncthreads();
  }

  const int c0 = tx*4;
#pragma unroll
  for (int i=0;i<8;i++){
    int gr = row0 + ty*8 + i;
    if (gr >= M) continue;
    float o0=acc[i][0], o1=acc[i][1], o2=acc[i][2], o3=acc[i][3];
    if (EPI == EPI_SCALE_CONST){
      o0*=svec[c0+0]; o1*=svec[c0+1]; o2*=svec[c0+2]; o3*=svec[c0+3];
    } else if (EPI == EPI_SCALE_GATHER){
      int g = gidx[gr];
      const float* p = P2 + (size_t)g*DD + c0;
      o0*=(svec[c0+0]+p[0]); o1*=(svec[c0+1]+p[1]);
      o2*=(svec[c0+2]+p[2]); o3*=(svec[c0+3]+p[3]);
    } else if (EPI == EPI_RELU){
      o0=fmaxf(o0,0.f); o1=fmaxf(o1,0.f); o2=fmaxf(o2,0.f); o3=fmaxf(o3,0.f);
    } else if (EPI == EPI_RELU_RES){
      us4 r = *(const us4*)(Rb + (size_t)gr*DD + c0);
      o0=fmaxf(o0,0.f)+b2f(r.x); o1=fmaxf(o1,0.f)+b2f(r.y);
      o2=fmaxf(o2,0.f)+b2f(r.z); o3=fmaxf(o3,0.f)+b2f(r.w);
    }
    if (OUTB){
      unsigned short* Cb = (unsigned short*)Cv;
      us4 o; o.x=f2b(o0); o.y=f2b(o1); o.z=f2b(o2); o.w=f2b(o3);
      *(us4*)(Cb + (size_t)gr*DD + c0) = o;
    } else {
      *(float4*)((float*)Cv + (size_t)gr*DD + c0) = make_float4(o0,o1,o2,o3);
    }
  }
}

// Static param-name graph -> base params. base: [0..7]=tw,[8..15]=n1,[16..23]=e1,
// [24..151]=n2,[152..279]=e2
__global__ __launch_bounds__(256) void k_static(
    const void* __restrict__ emb, const int* __restrict__ svals,
    const int* __restrict__ ssrc, const int* __restrict__ sdst,
    const void* __restrict__ u, const void* __restrict__ W2,
    const void* __restrict__ W1, float* __restrict__ base, int nsrc,
    const int* __restrict__ dflag)
{
  __shared__ float sagg[15][128];
  __shared__ float ssc[15][16];
  __shared__ float sww[15][16];
  const bool wf32 = (*dflag) != 0;
  const int t = threadIdx.x;
  for (int i=t;i<15*128;i+=256) ((float*)sagg)[i]=0.f;
  __syncthreads();
  if (t < 128){
    for (int i=0;i<nsrc;i++){
      int row = sdst[i]; int vr = svals[ssrc[i]];
      sagg[row][t] += gld(emb, (size_t)vr*DD + t, wf32);
    }
  }
  __syncthreads();
  if (t < 240){
    int n = t>>4, l = t&15;
    float a=0.f;
    for (int d=0;d<128;d++) a += sagg[n][d]*gld(u, l*128+d, wf32);
    ssc[n][l] = a * 0.08838834764831845f;
  }
  __syncthreads();
  if (t < 15){
    float mx=-1e30f;
    for (int l=0;l<16;l++) mx = fmaxf(mx, ssc[t][l]);
    float s=0.f;
    for (int l=0;l<16;l++){ float e=__expf(ssc[t][l]-mx); sww[t][l]=e; s+=e; }
    float inv = 1.f/s;
    for (int l=0;l<16;l++) sww[t][l]*=inv;
  }
  __syncthreads();
  if (t < 8){
    float a=0.f,b=0.f,c=0.f;
    for (int l=0;l<16;l++){
      float wv = gld(W1, l*8+t, wf32);
      a += sww[0][l]*wv; b += sww[3][l]*wv; c += sww[9][l]*wv;
    }
    base[t]=a; base[8+t]=b; base[16+t]=c;
  }
  if (t < 128){
    float a=0.f,b=0.f;
    for (int l=0;l<16;l++){
      float wv = gld(W2, l*128+t, wf32);
      a += sww[6][l]*wv; b += sww[12][l]*wv;
    }
    base[24+t]=a; base[152+t]=b;
  }
}

template<bool OUTB>
__global__ __launch_bounds__(256) void gather_rows(
    const void* __restrict__ emb, const int* __restrict__ vals,
    void* __restrict__ dstv, int n, const int* __restrict__ dflag)
{
  const bool wf32 = (*dflag) != 0;
  int i = blockIdx.x*256 + threadIdx.x;
  if (i >= n*16) return;
  int r = i>>4, c = (i&15)*8;
  int vr = vals[r];
  float vb[8];
  if (wf32){
    float4 f0 = *(const float4*)((const float*)emb + (size_t)vr*DD + c);
    float4 f1 = *(const float4*)((const float*)emb + (size_t)vr*DD + c + 4);
    vb[0]=f0.x; vb[1]=f0.y; vb[2]=f0.z; vb[3]=f0.w;
    vb[4]=f1.x; vb[5]=f1.y; vb[6]=f1.z; vb[7]=f1.w;
  } else {
    uint4 raw = *(const uint4*)((const unsigned short*)emb + (size_t)vr*DD + c);
    const unsigned short* hw = (const unsigned short*)&raw;
#pragma unroll
    for (int j=0;j<8;j++) vb[j] = b2f(hw[j]);
  }
  if (OUTB){
    unsigned short* d = (unsigned short*)dstv + (size_t)r*DD + c;
    us4 o0, o1;
    o0.x=f2b(vb[0]); o0.y=f2b(vb[1]); o0.z=f2b(vb[2]); o0.w=f2b(vb[3]);
    o1.x=f2b(vb[4]); o1.y=f2b(vb[5]); o1.z=f2b(vb[6]); o1.w=f2b(vb[7]);
    *(us4*)d = o0; *(us4*)(d+4) = o1;
  } else {
    float* d = (float*)dstv + (size_t)r*DD + c;
    *(float4*)d     = make_float4(vb[0],vb[1],vb[2],vb[3]);
    *(float4*)(d+4) = make_float4(vb[4],vb[5],vb[6],vb[7]);
  }
}

__global__ __launch_bounds__(256) void zerof(float* __restrict__ p, long n4){
  long i = (long)blockIdx.x*256 + threadIdx.x;
  if (i < n4) ((float4*)p)[i] = make_float4(0.f,0.f,0.f,0.f);
}

__global__ __launch_bounds__(256) void edge_meta(
    const int* __restrict__ src, const int* __restrict__ dst,
    const unsigned short* __restrict__ qm, const unsigned short* __restrict__ kfm,
    const unsigned short* __restrict__ vm,
    const float* __restrict__ base, unsigned short* __restrict__ mef,
    float* __restrict__ z, float* __restrict__ agg, int E)
{
  int e = blockIdx.x*4 + (threadIdx.x>>6);
  if (e >= E) return;
  int lane = threadIdx.x & 63;
  int s = src[e], d = dst[e];
  const float* be2 = base+152; const float* be1 = base+16; const float* bn1 = base+8;
  size_t so=(size_t)s*DD, dq=(size_t)d*DD, eo=(size_t)e*DD;
  float ke0 = b2f(kfm[so+lane])    * be2[lane];
  float ke1 = b2f(kfm[so+64+lane]) * be2[64+lane];
  mef[eo+lane]=f2b(ke0); mef[eo+64+lane]=f2b(ke1);
  float p0 = b2f(qm[dq+lane])*ke0, p1 = b2f(qm[dq+64+lane])*ke1;
#pragma unroll
  for (int m=1;m<16;m<<=1){ p0 += __shfl_xor(p0,m,64); p1 += __shfl_xor(p1,m,64); }
  int h0 = lane>>4, h1 = h0+4;
  float s0 = p0*0.25f + be1[h0] + bn1[h0];
  float s1 = p1*0.25f + be1[h1] + bn1[h1];
  float e0 = __expf(s0), e1 = __expf(s1);
  if ((lane&15)==0){ atomicAdd(&z[(size_t)d*HH+h0], e0); atomicAdd(&z[(size_t)d*HH+h1], e1); }
  atomicAdd(&agg[dq+lane],    e0*b2f(vm[so+lane]));
  atomicAdd(&agg[dq+64+lane], e1*b2f(vm[so+64+lane]));
}

__global__ __launch_bounds__(256) void edge_scores(
    const int* __restrict__ src, const int* __restrict__ dst,
    const int* __restrict__ meid, const int* __restrict__ mnid,
    const unsigned short* __restrict__ q, const unsigned short* __restrict__ kf,
    const unsigned short* __restrict__ p2me, const unsigned short* __restrict__ p1me,
    const float* __restrict__ p1mn, const float* __restrict__ base,
    unsigned short* __restrict__ esc, float* __restrict__ z, int E)
{
  int e = blockIdx.x*4 + (threadIdx.x>>6);
  if (e >= E) return;
  int lane = threadIdx.x & 63;
  int s = src[e], d = dst[e], me = meid[e];
  int mn = mnid[d];
  const float* be2 = base+152; const float* be1 = base+16; const float* bn1 = base+8;
  size_t so=(size_t)s*DD, dq=(size_t)d*DD, mo=(size_t)me*DD;
  float ke0 = b2f(kf[so+lane])    * (be2[lane]    + b2f(p2me[mo+lane]));
  float ke1 = b2f(kf[so+64+lane]) * (be2[64+lane] + b2f(p2me[mo+64+lane]));
  float p0 = b2f(q[dq+lane])*ke0, p1 = b2f(q[dq+64+lane])*ke1;
#pragma unroll
  for (int m=1;m<16;m<<=1){ p0 += __shfl_xor(p0,m,64); p1 += __shfl_xor(p1,m,64); }
  int h0 = lane>>4, h1 = h0+4;
  float s0 = p0*0.25f + be1[h0] + b2f(p1me[(size_t)me*HH+h0]) + bn1[h0] + p1mn[(size_t)mn*HH+h0];
  float s1 = p1*0.25f + be1[h1] + b2f(p1me[(size_t)me*HH+h1]) + bn1[h1] + p1mn[(size_t)mn*HH+h1];
  float e0 = __expf(s0), e1 = __expf(s1);
  if ((lane&15)==0){
    esc[(size_t)e*HH+h0] = f2b(e0);
    esc[(size_t)e*HH+h1] = f2b(e1);
    atomicAdd(&z[(size_t)d*HH+h0], e0);
    atomicAdd(&z[(size_t)d*HH+h1], e1);
  }
}

__global__ __launch_bounds__(256) void edge_agg(
    const int* __restrict__ src, const int* __restrict__ dst,
    const unsigned short* __restrict__ esc, const unsigned short* __restrict__ v,
    float* __restrict__ agg, int E)
{
  int e = blockIdx.x*4 + (threadIdx.x>>6);
  if (e >= E) return;
  int lane = threadIdx.x & 63;
  int s = src[e], d = dst[e];
  size_t so=(size_t)s*DD, dq=(size_t)d*DD;
  int h0 = lane>>4;
  float e0 = b2f(esc[(size_t)e*HH+h0]);
  float e1 = b2f(esc[(size_t)e*HH+h0+4]);
  atomicAdd(&agg[dq+lane],    e0*b2f(v[so+lane]));
  atomicAdd(&agg[dq+64+lane], e1*b2f(v[so+64+lane]));
}

template<bool XB, bool PB>
__global__ __launch_bounds__(128) void learner(
    const void* __restrict__ X, const void* __restrict__ u,
    const void* __restrict__ W2, const void* __restrict__ W1,
    void* __restrict__ p2, void* __restrict__ p1, const int* __restrict__ dflag)
{
  __shared__ float sX[128];
  __shared__ float st[16];
  __shared__ float sw[16];
  const bool wf32 = (*dflag) != 0;
  const int m = blockIdx.x, t = threadIdx.x;
  if (XB) sX[t] = b2f(((const unsigned short*)X)[(size_t)m*DD + t]);
  else    sX[t] = ((const float*)X)[(size_t)m*DD + t];
  __syncthreads();
  int l = t>>3, j = t&7;
  float part = 0.f;
  for (int d=j*16; d<j*16+16; d++) part += sX[d]*gld(u, l*128+d, wf32);
  part += __shfl_xor(part,1,64); part += __shfl_xor(part,2,64); part += __shfl_xor(part,4,64);
  if (j==0) st[l] = part * 0.08838834764831845f;
  __syncthreads();
  float mx=-1e30f;
  for (int i=0;i<16;i++) mx = fmaxf(mx, st[i]);
  float ssum=0.f;
  for (int i=0;i<16;i++) ssum += __expf(st[i]-mx);
  float inv = 1.f/ssum;
  if (t<16) sw[t] = __expf(st[t]-mx)*inv;
  __syncthreads();
  float a=0.f;
  for (int i=0;i<16;i++) a += sw[i]*gld(W2, i*128+t, wf32);
  if (PB) ((unsigned short*)p2)[(size_t)m*DD+t] = f2b(a);
  else    ((float*)p2)[(size_t)m*DD+t] = a;
  if (t<8){
    float bb=0.f;
    for (int i=0;i<16;i++) bb += sw[i]*gld(W1, i*8+t, wf32);
    if (PB) ((unsigned short*)p1)[(size_t)m*HH+t] = f2b(bb);
    else    ((float*)p1)[(size_t)m*HH+t] = bb;
  }
}

__global__ __launch_bounds__(256) void resadd(float* __restrict__ a, const float* __restrict__ b, int n){
  int i = blockIdx.x*256 + threadIdx.x;
  if (i < n) a[i] += b[i];
}

__global__ __launch_bounds__(256) void readout(
    const int* __restrict__ tgt, const int* __restrict__ mnid,
    const unsigned short* __restrict__ featb, const float* __restrict__ p1mn,
    const float* __restrict__ base, float* __restrict__ acc,
    void* __restrict__ out, int last, float invNB, int BT,
    const int* __restrict__ dflag)
{
  int t = blockIdx.x*256 + threadIdx.x;
  if (t >= BT) return;
  int idx = tgt[t]; int mn = mnid[idx];
  float logit = 0.f;
  for (int h=0;h<8;h++){
    float tw = base[h] + p1mn[(size_t)mn*HH + h];
    float srow = 0.f;
    for (int k=0;k<16;k++) srow += b2f(featb[(size_t)idx*DD + h*16 + k]);
    logit += tw*srow;
  }
  if (!last) acc[t] = logit;
  else {
    float r = (acc[t] + logit) * invNB;
    if ((*dflag) != 0) ((float*)out)[t] = r;
    else ((__hip_bfloat16*)out)[t] = __float2bfloat16(r);
  }
}

extern "C" void kernel_launch(void* const* d_in, const int* in_sizes, int n_in,
                              void* d_out, int out_size, void* d_ws, size_t ws_size,
                              hipStream_t stream) {
  const void* emb   = d_in[0];
  const void* u     = d_in[1];
  const void* W2lat = d_in[2];
  const void* W1lat = d_in[3];
  const void* Wmat[8] = { d_in[4], d_in[5], d_in[6], d_in[7],
                          d_in[8], d_in[9], d_in[10], d_in[11] };
  const int* node_vals      = (const int*)d_in[12];
  const int* meta_node_vals = (const int*)d_in[13];
  const int* src            = (const int*)d_in[14];
  const int* dst            = (const int*)d_in[15];
  const int* meta_src       = (const int*)d_in[16];
  const int* meta_dst       = (const int*)d_in[17];
  const int* meta_node_id   = (const int*)d_in[18];
  const int* meta_edge_id   = (const int*)d_in[19];
  const int* target_idx     = (const int*)d_in[20];
  const int* static_vals    = (const int*)d_in[21];
  const int* static_src     = (const int*)d_in[22];
  const int* static_dst     = (const int*)d_in[23];

  const int N  = in_sizes[12];
  const int MN = in_sizes[13];
  const int E  = in_sizes[14];
  const int ME = in_sizes[16];
  const int BT = in_sizes[20];
  const int NSRC = in_sizes[22];
  const int NB = in_sizes[8] / (DD*DD);

  float* ws = (float*)d_ws;
  size_t off = 0;
  auto allocf = [&](size_t n){ float* p = ws + off; off += n; return p; };
  auto allocb = [&](size_t n){ unsigned short* p = (unsigned short*)(ws + off); off += (n+1)/2; return p; };
  int*            dflag = (int*)ws; off += 4;
  unsigned short* feat  = allocb((size_t)N*DD);
  unsigned short* q     = allocb((size_t)N*DD);   // after pass A, agg (f32) aliases q+kf
  unsigned short* kf    = allocb((size_t)N*DD);
  float*          agg   = (float*)q;
  unsigned short* v     = allocb((size_t)N*DD);
  unsigned short* esc   = allocb((size_t)E*HH);
  float*          z     = allocf((size_t)N*HH);
  float*          meta_feat= allocf((size_t)MN*DD);
  float*          agg_m = allocf((size_t)MN*DD);  // z_m contiguous follows
  float*          z_m   = allocf((size_t)MN*HH);
  unsigned short* q_m   = allocb((size_t)MN*DD);
  unsigned short* kf_m  = allocb((size_t)MN*DD);
  unsigned short* v_m   = allocb((size_t)MN*DD);
  float*          meta_out = allocf((size_t)MN*DD);
  unsigned short* mef   = allocb((size_t)ME*DD);
  float*          p2mn  = allocf((size_t)MN*DD);
  float*          p1mn  = allocf((size_t)MN*HH);
  unsigned short* p2me  = allocb((size_t)ME*DD);
  unsigned short* p1me  = allocb((size_t)ME*HH);
  float*          base  = allocf(280);
  float*          acc   = allocf((size_t)BT);
  unsigned short* wstage= allocb((size_t)8*DD*DD);   // per-iter bf16 weight staging
  (void)ws_size; (void)n_in; (void)out_size;

  const float* base_n2 = base + 24;

  k_detect<<<1,64,0,stream>>>((const unsigned short*)emb, dflag);
  k_static<<<1,256,0,stream>>>(emb, static_vals, static_src, static_dst,
                               u, W2lat, W1lat, base, NSRC, dflag);
  gather_rows<true ><<<(N*16+255)/256,256,0,stream>>>(emb, node_vals, feat, N, dflag);
  gather_rows<false><<<(MN*16+255)/256,256,0,stream>>>(emb, meta_node_vals, meta_feat, MN, dflag);

  const int gm = (MN+63)/64;
  const int gN = (N+63)/64;
  const long nz_agg  = (long)N*DD/4;
  const long nz_z    = (long)N*HH/4;
  const long nz_meta = ((long)MN*DD + (long)MN*HH)/4;
  const float invNB = 1.0f/(float)NB;

  for (int b=0;b<NB;b++){
    const size_t bo = (size_t)b*DD*DD;
    for (int wi=0; wi<8; wi++)
      w_repack<<<64,256,0,stream>>>(Wmat[wi], wstage + (size_t)wi*DD*DD, bo, dflag);
    const unsigned short* wq_m = wstage + 0*DD*DD;
    const unsigned short* wk_m = wstage + 1*DD*DD;
    const unsigned short* wv_m = wstage + 2*DD*DD;
    const unsigned short* wo_m = wstage + 3*DD*DD;
    const unsigned short* wqb  = wstage + 4*DD*DD;
    const unsigned short* wkb  = wstage + 5*DD*DD;
    const unsigned short* wvb  = wstage + 6*DD*DD;
    const unsigned short* wob  = wstage + 7*DD*DD;

    // ---- meta conv (broadcast base params) ----
    gemm128<EPI_SCALE_CONST,false,false,true><<<gm,256,0,stream>>>(meta_feat, wq_m, q_m, MN,
        nullptr, base_n2, nullptr, nullptr, nullptr);
    gemm128<EPI_STORE,false,false,true><<<gm,256,0,stream>>>(meta_feat, wk_m, kf_m, MN,
        nullptr, nullptr, nullptr, nullptr, nullptr);
    gemm128<EPI_STORE,false,false,true><<<gm,256,0,stream>>>(meta_feat, wv_m, v_m, MN,
        nullptr, nullptr, nullptr, nullptr, nullptr);
    zerof<<<(int)((nz_meta+255)/256),256,0,stream>>>(agg_m, nz_meta);
    edge_meta<<<(ME+3)/4,256,0,stream>>>(meta_src, meta_dst, q_m, kf_m, v_m,
        base, mef, z_m, agg_m, ME);
    gemm128<EPI_RELU,true,false,false><<<gm,256,0,stream>>>(agg_m, wo_m, meta_out, MN,
        z_m, nullptr, nullptr, nullptr, nullptr);

    // ---- meta learners (pre-residual conv outputs) ----
    learner<false,false><<<MN,128,0,stream>>>(meta_out, u, W2lat, W1lat, p2mn, p1mn, dflag);
    learner<true ,true ><<<ME,128,0,stream>>>(mef,      u, W2lat, W1lat, p2me, p1me, dflag);
    resadd<<<(MN*DD+255)/256,256,0,stream>>>(meta_feat, meta_out, MN*DD);

    // ---- big conv ----
    gemm128<EPI_SCALE_GATHER,false,true,true><<<gN,256,0,stream>>>(feat, wqb, q, N,
        nullptr, base_n2, p2mn, meta_node_id, nullptr);
    gemm128<EPI_STORE,false,true,true><<<gN,256,0,stream>>>(feat, wkb, kf, N,
        nullptr, nullptr, nullptr, nullptr, nullptr);
    gemm128<EPI_STORE,false,true,true><<<gN,256,0,stream>>>(feat, wvb, v, N,
        nullptr, nullptr, nullptr, nullptr, nullptr);
    zerof<<<(int)((nz_z+255)/256),256,0,stream>>>(z, nz_z);
    edge_scores<<<(E+3)/4,256,0,stream>>>(src, dst, meta_edge_id, meta_node_id,
        q, kf, p2me, p1me, p1mn, base, esc, z, E);
    zerof<<<(int)((nz_agg+255)/256),256,0,stream>>>(agg, nz_agg);
    edge_agg<<<(E+3)/4,256,0,stream>>>(src, dst, esc, v, agg, E);
    gemm128<EPI_RELU_RES,true,false,true><<<gN,256,0,stream>>>(agg, wob, feat, N,
        z, nullptr, nullptr, nullptr, feat);

    // ---- readout ----
    readout<<<(BT+255)/256,256,0,stream>>>(target_idx, meta_node_id, feat, p1mn,
        base, acc, d_out, (b==NB-1) ? 1 : 0, invNB, BT, dflag);
  }
}

// Round 5
// 1463.730 us; speedup vs baseline: 1.4069x; 1.4069x over previous
//
#include <hip/hip_runtime.h>
#include <hip/hip_bf16.h>

#define DD   128
#define HH   8

__device__ __forceinline__ float b2f(unsigned short v){
  union { unsigned int u; float f; } x; x.u = ((unsigned int)v) << 16; return x.f;
}
__device__ __forceinline__ unsigned short f2b(float f){
  __hip_bfloat16 h = __float2bfloat16(f);
  return *(unsigned short*)&h;
}
struct __align__(8) us4 { unsigned short x,y,z,w; };

__device__ __forceinline__ float gld(const void* p, size_t i, bool f32){
  if (f32) return ((const float*)p)[i];
  return b2f(((const unsigned short*)p)[i]);
}

// Detect input float dtype. emb ~ N(0,1)*0.05. If f32, odd ushorts are mantissa
// garbage -> huge "bf16" values. flag=1 -> inputs are f32.
__global__ __launch_bounds__(64) void k_detect(const unsigned short* __restrict__ emb,
                                               int* __restrict__ flag){
  int t = threadIdx.x;
  float m = 0.f;
  for (int i=t; i<128; i+=64){
    float x = fabsf(b2f(emb[i]));
    if (x < 1e30f) m = fmaxf(m, x);
  }
#pragma unroll
  for (int s=1;s<64;s<<=1) m = fmaxf(m, __shfl_xor(m, s, 64));
  if (t==0) *flag = (m > 1e4f) ? 1 : 0;
}

// stage[i] = bf16( W[bo+i] ), dtype per flag.
__global__ __launch_bounds__(256) void w_repack(
    const void* __restrict__ W, unsigned short* __restrict__ stage,
    size_t bo, const int* __restrict__ dflag)
{
  const bool wf32 = (*dflag) != 0;
  int i = blockIdx.x*256 + threadIdx.x;
  if (i >= DD*DD) return;
  float x;
  if (wf32) x = ((const float*)W)[bo + i];
  else      x = b2f(((const unsigned short*)W)[bo + i]);
  stage[i] = f2b(x);
}

enum { EPI_STORE=0, EPI_SCALE_CONST=1, EPI_SCALE_GATHER=2, EPI_RELU=3, EPI_RELU_RES=4 };

// C[M,128] = epi( prologue(A)[M,128] @ B[128,128] ), B bf16 staged.
template<int EPI, bool NORM, bool INB, bool OUTB>
__global__ __launch_bounds__(256) void gemm128(
    const void* __restrict__ Av, const unsigned short* __restrict__ B,
    void* __restrict__ Cv, int M,
    const float* __restrict__ z, const float* __restrict__ svec,
    const float* __restrict__ P2, const int* __restrict__ gidx,
    const unsigned short* __restrict__ Rb)
{
  __shared__ float As[32][68];
  __shared__ float Bs[32][128];
  const int tid = threadIdx.x;
  const int tx = tid & 31, ty = tid >> 5;
  const int row0 = blockIdx.x * 64;
  float acc[8][4];
#pragma unroll
  for (int i=0;i<8;i++){ acc[i][0]=0.f; acc[i][1]=0.f; acc[i][2]=0.f; acc[i][3]=0.f; }
  const int ar = tid >> 3, ac = (tid & 7) * 4;

  for (int k0=0;k0<128;k0+=32){
#pragma unroll
    for (int i=0;i<2;i++){
      int r = ar + i*32;
      int gr = row0 + r;
      float4 val = make_float4(0.f,0.f,0.f,0.f);
      if (gr < M){
        if (INB){
          us4 raw = *(const us4*)((const unsigned short*)Av + (size_t)gr*DD + k0 + ac);
          val = make_float4(b2f(raw.x), b2f(raw.y), b2f(raw.z), b2f(raw.w));
        } else {
          val = *(const float4*)((const float*)Av + (size_t)gr*DD + k0 + ac);
          if (NORM){
            float s = 1.0f / (z[(size_t)gr*HH + ((k0+ac)>>4)] + 1e-9f);
            val.x*=s; val.y*=s; val.z*=s; val.w*=s;
          }
        }
      }
      As[ac+0][r]=val.x; As[ac+1][r]=val.y; As[ac+2][r]=val.z; As[ac+3][r]=val.w;
    }
#pragma unroll
    for (int i=0;i<2;i++){
      int idx = tid + i*256;
      int l = idx * 8;
      int kr = l >> 7, c = l & 127;
      uint4 raw = *(const uint4*)(B + (size_t)(k0+kr)*DD + c);
      const unsigned short* hw = (const unsigned short*)&raw;
#pragma unroll
      for (int j=0;j<8;j++) Bs[kr][c+j] = b2f(hw[j]);
    }
    __syncthreads();
#pragma unroll
    for (int kk=0;kk<32;kk++){
      float4 a0 = *(const float4*)&As[kk][ty*8];
      float4 a1 = *(const float4*)&As[kk][ty*8+4];
      float4 b  = *(const float4*)&Bs[kk][tx*4];
      float av[8] = {a0.x,a0.y,a0.z,a0.w,a1.x,a1.y,a1.z,a1.w};
#pragma unroll
      for (int i=0;i<8;i++){
        acc[i][0] += av[i]*b.x; acc[i][1] += av[i]*b.y;
        acc[i][2] += av[i]*b.z; acc[i][3] += av[i]*b.w;
      }
    }
    __syncthreads();
  }

  const int c0 = tx*4;
#pragma unroll
  for (int i=0;i<8;i++){
    int gr = row0 + ty*8 + i;
    if (gr >= M) continue;
    float o0=acc[i][0], o1=acc[i][1], o2=acc[i][2], o3=acc[i][3];
    if (EPI == EPI_SCALE_CONST){
      o0*=svec[c0+0]; o1*=svec[c0+1]; o2*=svec[c0+2]; o3*=svec[c0+3];
    } else if (EPI == EPI_SCALE_GATHER){
      int g = gidx[gr];
      const float* p = P2 + (size_t)g*DD + c0;
      o0*=(svec[c0+0]+p[0]); o1*=(svec[c0+1]+p[1]);
      o2*=(svec[c0+2]+p[2]); o3*=(svec[c0+3]+p[3]);
    } else if (EPI == EPI_RELU){
      o0=fmaxf(o0,0.f); o1=fmaxf(o1,0.f); o2=fmaxf(o2,0.f); o3=fmaxf(o3,0.f);
    } else if (EPI == EPI_RELU_RES){
      us4 r = *(const us4*)(Rb + (size_t)gr*DD + c0);
      o0=fmaxf(o0,0.f)+b2f(r.x); o1=fmaxf(o1,0.f)+b2f(r.y);
      o2=fmaxf(o2,0.f)+b2f(r.z); o3=fmaxf(o3,0.f)+b2f(r.w);
    }
    if (OUTB){
      unsigned short* Cb = (unsigned short*)Cv;
      us4 o; o.x=f2b(o0); o.y=f2b(o1); o.z=f2b(o2); o.w=f2b(o3);
      *(us4*)(Cb + (size_t)gr*DD + c0) = o;
    } else {
      *(float4*)((float*)Cv + (size_t)gr*DD + c0) = make_float4(o0,o1,o2,o3);
    }
  }
}

// Static param-name graph -> base params. base: [0..7]=tw,[8..15]=n1,[16..23]=e1,
// [24..151]=n2,[152..279]=e2
__global__ __launch_bounds__(256) void k_static(
    const void* __restrict__ emb, const int* __restrict__ svals,
    const int* __restrict__ ssrc, const int* __restrict__ sdst,
    const void* __restrict__ u, const void* __restrict__ W2,
    const void* __restrict__ W1, float* __restrict__ base, int nsrc,
    const int* __restrict__ dflag)
{
  __shared__ float sagg[15][128];
  __shared__ float ssc[15][16];
  __shared__ float sww[15][16];
  const bool wf32 = (*dflag) != 0;
  const int t = threadIdx.x;
  for (int i=t;i<15*128;i+=256) ((float*)sagg)[i]=0.f;
  __syncthreads();
  if (t < 128){
    for (int i=0;i<nsrc;i++){
      int row = sdst[i]; int vr = svals[ssrc[i]];
      sagg[row][t] += gld(emb, (size_t)vr*DD + t, wf32);
    }
  }
  __syncthreads();
  if (t < 240){
    int n = t>>4, l = t&15;
    float a=0.f;
    for (int d=0;d<128;d++) a += sagg[n][d]*gld(u, l*128+d, wf32);
    ssc[n][l] = a * 0.08838834764831845f;
  }
  __syncthreads();
  if (t < 15){
    float mx=-1e30f;
    for (int l=0;l<16;l++) mx = fmaxf(mx, ssc[t][l]);
    float s=0.f;
    for (int l=0;l<16;l++){ float e=__expf(ssc[t][l]-mx); sww[t][l]=e; s+=e; }
    float inv = 1.f/s;
    for (int l=0;l<16;l++) sww[t][l]*=inv;
  }
  __syncthreads();
  if (t < 8){
    float a=0.f,b=0.f,c=0.f;
    for (int l=0;l<16;l++){
      float wv = gld(W1, l*8+t, wf32);
      a += sww[0][l]*wv; b += sww[3][l]*wv; c += sww[9][l]*wv;
    }
    base[t]=a; base[8+t]=b; base[16+t]=c;
  }
  if (t < 128){
    float a=0.f,b=0.f;
    for (int l=0;l<16;l++){
      float wv = gld(W2, l*128+t, wf32);
      a += sww[6][l]*wv; b += sww[12][l]*wv;
    }
    base[24+t]=a; base[152+t]=b;
  }
}

template<bool OUTB>
__global__ __launch_bounds__(256) void gather_rows(
    const void* __restrict__ emb, const int* __restrict__ vals,
    void* __restrict__ dstv, int n, const int* __restrict__ dflag)
{
  const bool wf32 = (*dflag) != 0;
  int i = blockIdx.x*256 + threadIdx.x;
  if (i >= n*16) return;
  int r = i>>4, c = (i&15)*8;
  int vr = vals[r];
  float vb[8];
  if (wf32){
    float4 f0 = *(const float4*)((const float*)emb + (size_t)vr*DD + c);
    float4 f1 = *(const float4*)((const float*)emb + (size_t)vr*DD + c + 4);
    vb[0]=f0.x; vb[1]=f0.y; vb[2]=f0.z; vb[3]=f0.w;
    vb[4]=f1.x; vb[5]=f1.y; vb[6]=f1.z; vb[7]=f1.w;
  } else {
    uint4 raw = *(const uint4*)((const unsigned short*)emb + (size_t)vr*DD + c);
    const unsigned short* hw = (const unsigned short*)&raw;
#pragma unroll
    for (int j=0;j<8;j++) vb[j] = b2f(hw[j]);
  }
  if (OUTB){
    unsigned short* d = (unsigned short*)dstv + (size_t)r*DD + c;
    us4 o0, o1;
    o0.x=f2b(vb[0]); o0.y=f2b(vb[1]); o0.z=f2b(vb[2]); o0.w=f2b(vb[3]);
    o1.x=f2b(vb[4]); o1.y=f2b(vb[5]); o1.z=f2b(vb[6]); o1.w=f2b(vb[7]);
    *(us4*)d = o0; *(us4*)(d+4) = o1;
  } else {
    float* d = (float*)dstv + (size_t)r*DD + c;
    *(float4*)d     = make_float4(vb[0],vb[1],vb[2],vb[3]);
    *(float4*)(d+4) = make_float4(vb[4],vb[5],vb[6],vb[7]);
  }
}

__global__ __launch_bounds__(256) void zerof(float* __restrict__ p, long n4){
  long i = (long)blockIdx.x*256 + threadIdx.x;
  if (i < n4) ((float4*)p)[i] = make_float4(0.f,0.f,0.f,0.f);
}
__global__ __launch_bounds__(256) void zeroi(int* __restrict__ p, int n){
  int i = blockIdx.x*256 + threadIdx.x;
  if (i < n) p[i] = 0;
}

// ---------------- CSR build (by dst) ----------------
__global__ __launch_bounds__(256) void k_hist(const int* __restrict__ dst,
                                              int* __restrict__ deg, int E){
  int i = blockIdx.x*256 + threadIdx.x;
  if (i < E) atomicAdd(&deg[dst[i]], 1);
}

// block scans 1024 elems (256 thr x 4); exclusive prefix into rowptr; block total to bsum
__global__ __launch_bounds__(256) void k_scan1(const int* __restrict__ deg,
                                               int* __restrict__ rowptr,
                                               int* __restrict__ bsum, int n){
  __shared__ int ls[256];
  int b = blockIdx.x, t = threadIdx.x;
  int base = b*1024 + t*4;
  int v0 = (base+0<n)?deg[base+0]:0;
  int v1 = (base+1<n)?deg[base+1]:0;
  int v2 = (base+2<n)?deg[base+2]:0;
  int v3 = (base+3<n)?deg[base+3]:0;
  int tsum = v0+v1+v2+v3;
  ls[t] = tsum; __syncthreads();
  for (int o=1;o<256;o<<=1){
    int x = (t>=o) ? ls[t-o] : 0;
    __syncthreads();
    ls[t] += x;
    __syncthreads();
  }
  int excl = ls[t]-tsum;
  if (t==255) bsum[b] = ls[255];
  if (base+0<n) rowptr[base+0]=excl;
  if (base+1<n) rowptr[base+1]=excl+v0;
  if (base+2<n) rowptr[base+2]=excl+v0+v1;
  if (base+3<n) rowptr[base+3]=excl+v0+v1+v2;
}

// single-thread scan of block sums (nb ~ 98); sets rowptr[n] = total
__global__ __launch_bounds__(64) void k_scan2(int* __restrict__ bsum, int nb,
                                              int* __restrict__ rowptr, int n){
  if (threadIdx.x==0){
    int run = 0;
    for (int b=0;b<nb;b++){ int x = bsum[b]; bsum[b] = run; run += x; }
    rowptr[n] = run;
  }
}

// add block offsets; copy into cursor
__global__ __launch_bounds__(256) void k_scan3(int* __restrict__ rowptr,
                                               const int* __restrict__ bsum,
                                               int* __restrict__ cursor, int n){
  int i = blockIdx.x*256 + threadIdx.x;
  if (i < n){
    int r = rowptr[i] + bsum[i>>10];
    rowptr[i] = r;
    cursor[i] = r;
  }
}

__global__ __launch_bounds__(256) void k_scatter(const int* __restrict__ dst,
                                                 int* __restrict__ cursor,
                                                 int* __restrict__ eidx, int E){
  int e = blockIdx.x*256 + threadIdx.x;
  if (e < E){
    int p = atomicAdd(&cursor[dst[e]], 1);
    eidx[p] = e;
  }
}

// ---------------- meta-graph edges (tiny, atomic version kept) ----------------
__global__ __launch_bounds__(256) void edge_meta(
    const int* __restrict__ src, const int* __restrict__ dst,
    const unsigned short* __restrict__ qm, const unsigned short* __restrict__ kfm,
    const unsigned short* __restrict__ vm,
    const float* __restrict__ base, unsigned short* __restrict__ mef,
    float* __restrict__ z, float* __restrict__ agg, int E)
{
  int e = blockIdx.x*4 + (threadIdx.x>>6);
  if (e >= E) return;
  int lane = threadIdx.x & 63;
  int s = src[e], d = dst[e];
  const float* be2 = base+152; const float* be1 = base+16; const float* bn1 = base+8;
  size_t so=(size_t)s*DD, dq=(size_t)d*DD, eo=(size_t)e*DD;
  float ke0 = b2f(kfm[so+lane])    * be2[lane];
  float ke1 = b2f(kfm[so+64+lane]) * be2[64+lane];
  mef[eo+lane]=f2b(ke0); mef[eo+64+lane]=f2b(ke1);
  float p0 = b2f(qm[dq+lane])*ke0, p1 = b2f(qm[dq+64+lane])*ke1;
#pragma unroll
  for (int m=1;m<16;m<<=1){ p0 += __shfl_xor(p0,m,64); p1 += __shfl_xor(p1,m,64); }
  int h0 = lane>>4, h1 = h0+4;
  float s0 = p0*0.25f + be1[h0] + bn1[h0];
  float s1 = p1*0.25f + be1[h1] + bn1[h1];
  float e0 = __expf(s0), e1 = __expf(s1);
  if ((lane&15)==0){ atomicAdd(&z[(size_t)d*HH+h0], e0); atomicAdd(&z[(size_t)d*HH+h1], e1); }
  atomicAdd(&agg[dq+lane],    e0*b2f(vm[so+lane]));
  atomicAdd(&agg[dq+64+lane], e1*b2f(vm[so+64+lane]));
}

// ---------------- big-graph edges: dst-centric CSR, atomic-free ----------------
// one wave per dst node: scores -> esc (bf16), z written non-atomically
__global__ __launch_bounds__(256) void edge_scores_csr(
    const int* __restrict__ rowptr, const int* __restrict__ eidx,
    const int* __restrict__ src, const int* __restrict__ meid,
    const int* __restrict__ mnid,
    const unsigned short* __restrict__ q, const unsigned short* __restrict__ kf,
    const unsigned short* __restrict__ p2me, const unsigned short* __restrict__ p1me,
    const float* __restrict__ p1mn, const float* __restrict__ base,
    unsigned short* __restrict__ esc, float* __restrict__ z, int N)
{
  int d = blockIdx.x*4 + (threadIdx.x>>6);
  if (d >= N) return;
  int lane = threadIdx.x & 63;
  size_t dq=(size_t)d*DD;
  const float* be2 = base+152; const float* be1 = base+16; const float* bn1 = base+8;
  float q0 = b2f(q[dq+lane]), q1 = b2f(q[dq+64+lane]);
  int mn = mnid[d];
  int h0 = lane>>4, h1 = h0+4;
  float bias0 = be1[h0] + bn1[h0] + p1mn[(size_t)mn*HH+h0];
  float bias1 = be1[h1] + bn1[h1] + p1mn[(size_t)mn*HH+h1];
  float w2a = be2[lane], w2b = be2[64+lane];
  float z0 = 0.f, z1 = 0.f;
  int i0 = rowptr[d], i1 = rowptr[d+1];
  for (int i=i0; i<i1; i++){
    int e = eidx[i];
    int s = src[e], me = meid[e];
    size_t so=(size_t)s*DD, mo=(size_t)me*DD;
    float ke0 = b2f(kf[so+lane])    * (w2a + b2f(p2me[mo+lane]));
    float ke1 = b2f(kf[so+64+lane]) * (w2b + b2f(p2me[mo+64+lane]));
    float p0 = q0*ke0, p1 = q1*ke1;
#pragma unroll
    for (int m=1;m<16;m<<=1){ p0 += __shfl_xor(p0,m,64); p1 += __shfl_xor(p1,m,64); }
    float s0 = p0*0.25f + bias0 + b2f(p1me[(size_t)me*HH+h0]);
    float s1 = p1*0.25f + bias1 + b2f(p1me[(size_t)me*HH+h1]);
    float ex0 = __expf(s0), ex1 = __expf(s1);
    if ((lane&15)==0){
      esc[(size_t)e*HH+h0] = f2b(ex0);
      esc[(size_t)e*HH+h1] = f2b(ex1);
    }
    z0 += ex0; z1 += ex1;
  }
  if ((lane&15)==0){
    z[(size_t)d*HH+h0] = z0;
    z[(size_t)d*HH+h1] = z1;
  }
}

// one wave per dst node: agg[d] = sum_e esc[e]*v[src[e]] (non-atomic store)
__global__ __launch_bounds__(256) void edge_agg_csr(
    const int* __restrict__ rowptr, const int* __restrict__ eidx,
    const int* __restrict__ src,
    const unsigned short* __restrict__ esc, const unsigned short* __restrict__ v,
    float* __restrict__ agg, int N)
{
  int d = blockIdx.x*4 + (threadIdx.x>>6);
  if (d >= N) return;
  int lane = threadIdx.x & 63;
  int h0 = lane>>4;
  float a0 = 0.f, a1 = 0.f;
  int i0 = rowptr[d], i1 = rowptr[d+1];
  for (int i=i0; i<i1; i++){
    int e = eidx[i];
    int s = src[e];
    size_t so=(size_t)s*DD;
    float e0 = b2f(esc[(size_t)e*HH+h0]);
    float e1 = b2f(esc[(size_t)e*HH+h0+4]);
    a0 += e0*b2f(v[so+lane]);
    a1 += e1*b2f(v[so+64+lane]);
  }
  size_t dq=(size_t)d*DD;
  agg[dq+lane]    = a0;
  agg[dq+64+lane] = a1;
}

template<bool XB, bool PB>
__global__ __launch_bounds__(128) void learner(
    const void* __restrict__ X, const void* __restrict__ u,
    const void* __restrict__ W2, const void* __restrict__ W1,
    void* __restrict__ p2, void* __restrict__ p1, const int* __restrict__ dflag)
{
  __shared__ float sX[128];
  __shared__ float st[16];
  __shared__ float sw[16];
  const bool wf32 = (*dflag) != 0;
  const int m = blockIdx.x, t = threadIdx.x;
  if (XB) sX[t] = b2f(((const unsigned short*)X)[(size_t)m*DD + t]);
  else    sX[t] = ((const float*)X)[(size_t)m*DD + t];
  __syncthreads();
  int l = t>>3, j = t&7;
  float part = 0.f;
  for (int d=j*16; d<j*16+16; d++) part += sX[d]*gld(u, l*128+d, wf32);
  part += __shfl_xor(part,1,64); part += __shfl_xor(part,2,64); part += __shfl_xor(part,4,64);
  if (j==0) st[l] = part * 0.08838834764831845f;
  __syncthreads();
  float mx=-1e30f;
  for (int i=0;i<16;i++) mx = fmaxf(mx, st[i]);
  float ssum=0.f;
  for (int i=0;i<16;i++) ssum += __expf(st[i]-mx);
  float inv = 1.f/ssum;
  if (t<16) sw[t] = __expf(st[t]-mx)*inv;
  __syncthreads();
  float a=0.f;
  for (int i=0;i<16;i++) a += sw[i]*gld(W2, i*128+t, wf32);
  if (PB) ((unsigned short*)p2)[(size_t)m*DD+t] = f2b(a);
  else    ((float*)p2)[(size_t)m*DD+t] = a;
  if (t<8){
    float bb=0.f;
    for (int i=0;i<16;i++) bb += sw[i]*gld(W1, i*8+t, wf32);
    if (PB) ((unsigned short*)p1)[(size_t)m*HH+t] = f2b(bb);
    else    ((float*)p1)[(size_t)m*HH+t] = bb;
  }
}

__global__ __launch_bounds__(256) void resadd(float* __restrict__ a, const float* __restrict__ b, int n){
  int i = blockIdx.x*256 + threadIdx.x;
  if (i < n) a[i] += b[i];
}

__global__ __launch_bounds__(256) void readout(
    const int* __restrict__ tgt, const int* __restrict__ mnid,
    const unsigned short* __restrict__ featb, const float* __restrict__ p1mn,
    const float* __restrict__ base, float* __restrict__ acc,
    void* __restrict__ out, int last, float invNB, int BT,
    const int* __restrict__ dflag)
{
  int t = blockIdx.x*256 + threadIdx.x;
  if (t >= BT) return;
  int idx = tgt[t]; int mn = mnid[idx];
  float logit = 0.f;
  for (int h=0;h<8;h++){
    float tw = base[h] + p1mn[(size_t)mn*HH + h];
    float srow = 0.f;
    for (int k=0;k<16;k++) srow += b2f(featb[(size_t)idx*DD + h*16 + k]);
    logit += tw*srow;
  }
  if (!last) acc[t] = logit;
  else {
    float r = (acc[t] + logit) * invNB;
    if ((*dflag) != 0) ((float*)out)[t] = r;
    else ((__hip_bfloat16*)out)[t] = __float2bfloat16(r);
  }
}

extern "C" void kernel_launch(void* const* d_in, const int* in_sizes, int n_in,
                              void* d_out, int out_size, void* d_ws, size_t ws_size,
                              hipStream_t stream) {
  const void* emb   = d_in[0];
  const void* u     = d_in[1];
  const void* W2lat = d_in[2];
  const void* W1lat = d_in[3];
  const void* Wmat[8] = { d_in[4], d_in[5], d_in[6], d_in[7],
                          d_in[8], d_in[9], d_in[10], d_in[11] };
  const int* node_vals      = (const int*)d_in[12];
  const int* meta_node_vals = (const int*)d_in[13];
  const int* src            = (const int*)d_in[14];
  const int* dst            = (const int*)d_in[15];
  const int* meta_src       = (const int*)d_in[16];
  const int* meta_dst       = (const int*)d_in[17];
  const int* meta_node_id   = (const int*)d_in[18];
  const int* meta_edge_id   = (const int*)d_in[19];
  const int* target_idx     = (const int*)d_in[20];
  const int* static_vals    = (const int*)d_in[21];
  const int* static_src     = (const int*)d_in[22];
  const int* static_dst     = (const int*)d_in[23];

  const int N  = in_sizes[12];
  const int MN = in_sizes[13];
  const int E  = in_sizes[14];
  const int ME = in_sizes[16];
  const int BT = in_sizes[20];
  const int NSRC = in_sizes[22];
  const int NB = in_sizes[8] / (DD*DD);

  float* ws = (float*)d_ws;
  size_t off = 0;
  auto allocf = [&](size_t n){ float* p = ws + off; off += n; return p; };
  auto allocb = [&](size_t n){ unsigned short* p = (unsigned short*)(ws + off); off += (n+1)/2; return p; };
  auto alloci = [&](size_t n){ int* p = (int*)(ws + off); off += n; return p; };
  int*            dflag = (int*)ws; off += 4;
  unsigned short* feat  = allocb((size_t)N*DD);
  unsigned short* q     = allocb((size_t)N*DD);   // agg (f32) aliases q+kf after scores
  unsigned short* kf    = allocb((size_t)N*DD);
  float*          agg   = (float*)q;
  unsigned short* v     = allocb((size_t)N*DD);
  unsigned short* esc   = allocb((size_t)E*HH);
  float*          z     = allocf((size_t)N*HH);
  float*          meta_feat= allocf((size_t)MN*DD);
  float*          agg_m = allocf((size_t)MN*DD);  // z_m contiguous follows
  float*          z_m   = allocf((size_t)MN*HH);
  unsigned short* q_m   = allocb((size_t)MN*DD);
  unsigned short* kf_m  = allocb((size_t)MN*DD);
  unsigned short* v_m   = allocb((size_t)MN*DD);
  float*          meta_out = allocf((size_t)MN*DD);
  unsigned short* mef   = allocb((size_t)ME*DD);
  float*          p2mn  = allocf((size_t)MN*DD);
  float*          p1mn  = allocf((size_t)MN*HH);
  unsigned short* p2me  = allocb((size_t)ME*DD);
  unsigned short* p1me  = allocb((size_t)ME*HH);
  float*          base  = allocf(280);
  float*          acc   = allocf((size_t)BT);
  unsigned short* wstage= allocb((size_t)8*DD*DD);
  // CSR arrays
  int*            rowptr= alloci((size_t)N+1);
  int*            cursor= alloci((size_t)N);
  int*            deg   = alloci((size_t)N);
  int*            eidx  = alloci((size_t)E);
  const int nb_scan = (N + 1023)/1024;
  int*            bsum  = alloci((size_t)nb_scan);
  (void)ws_size; (void)n_in; (void)out_size;

  const float* base_n2 = base + 24;

  k_detect<<<1,64,0,stream>>>((const unsigned short*)emb, dflag);
  k_static<<<1,256,0,stream>>>(emb, static_vals, static_src, static_dst,
                               u, W2lat, W1lat, base, NSRC, dflag);
  gather_rows<true ><<<(N*16+255)/256,256,0,stream>>>(emb, node_vals, feat, N, dflag);
  gather_rows<false><<<(MN*16+255)/256,256,0,stream>>>(emb, meta_node_vals, meta_feat, MN, dflag);

  // ---- CSR build (by dst), once per call ----
  zeroi<<<(N+255)/256,256,0,stream>>>(deg, N);
  k_hist<<<(E+255)/256,256,0,stream>>>(dst, deg, E);
  k_scan1<<<nb_scan,256,0,stream>>>(deg, rowptr, bsum, N);
  k_scan2<<<1,64,0,stream>>>(bsum, nb_scan, rowptr, N);
  k_scan3<<<(N+255)/256,256,0,stream>>>(rowptr, bsum, cursor, N);
  k_scatter<<<(E+255)/256,256,0,stream>>>(dst, cursor, eidx, E);

  const int gm = (MN+63)/64;
  const int gN = (N+63)/64;
  const long nz_meta = ((long)MN*DD + (long)MN*HH)/4;
  const float invNB = 1.0f/(float)NB;

  for (int b=0;b<NB;b++){
    const size_t bo = (size_t)b*DD*DD;
    for (int wi=0; wi<8; wi++)
      w_repack<<<64,256,0,stream>>>(Wmat[wi], wstage + (size_t)wi*DD*DD, bo, dflag);
    const unsigned short* wq_m = wstage + 0*DD*DD;
    const unsigned short* wk_m = wstage + 1*DD*DD;
    const unsigned short* wv_m = wstage + 2*DD*DD;
    const unsigned short* wo_m = wstage + 3*DD*DD;
    const unsigned short* wqb  = wstage + 4*DD*DD;
    const unsigned short* wkb  = wstage + 5*DD*DD;
    const unsigned short* wvb  = wstage + 6*DD*DD;
    const unsigned short* wob  = wstage + 7*DD*DD;

    // ---- meta conv (broadcast base params) ----
    gemm128<EPI_SCALE_CONST,false,false,true><<<gm,256,0,stream>>>(meta_feat, wq_m, q_m, MN,
        nullptr, base_n2, nullptr, nullptr, nullptr);
    gemm128<EPI_STORE,false,false,true><<<gm,256,0,stream>>>(meta_feat, wk_m, kf_m, MN,
        nullptr, nullptr, nullptr, nullptr, nullptr);
    gemm128<EPI_STORE,false,false,true><<<gm,256,0,stream>>>(meta_feat, wv_m, v_m, MN,
        nullptr, nullptr, nullptr, nullptr, nullptr);
    zerof<<<(int)((nz_meta+255)/256),256,0,stream>>>(agg_m, nz_meta);
    edge_meta<<<(ME+3)/4,256,0,stream>>>(meta_src, meta_dst, q_m, kf_m, v_m,
        base, mef, z_m, agg_m, ME);
    gemm128<EPI_RELU,true,false,false><<<gm,256,0,stream>>>(agg_m, wo_m, meta_out, MN,
        z_m, nullptr, nullptr, nullptr, nullptr);

    // ---- meta learners (pre-residual conv outputs) ----
    learner<false,false><<<MN,128,0,stream>>>(meta_out, u, W2lat, W1lat, p2mn, p1mn, dflag);
    learner<true ,true ><<<ME,128,0,stream>>>(mef,      u, W2lat, W1lat, p2me, p1me, dflag);
    resadd<<<(MN*DD+255)/256,256,0,stream>>>(meta_feat, meta_out, MN*DD);

    // ---- big conv ----
    gemm128<EPI_SCALE_GATHER,false,true,true><<<gN,256,0,stream>>>(feat, wqb, q, N,
        nullptr, base_n2, p2mn, meta_node_id, nullptr);
    gemm128<EPI_STORE,false,true,true><<<gN,256,0,stream>>>(feat, wkb, kf, N,
        nullptr, nullptr, nullptr, nullptr, nullptr);
    gemm128<EPI_STORE,false,true,true><<<gN,256,0,stream>>>(feat, wvb, v, N,
        nullptr, nullptr, nullptr, nullptr, nullptr);
    edge_scores_csr<<<(N+3)/4,256,0,stream>>>(rowptr, eidx, src, meta_edge_id,
        meta_node_id, q, kf, p2me, p1me, p1mn, base, esc, z, N);
    // q/kf dead -> agg (f32) reuses their space; every agg row is overwritten
    edge_agg_csr<<<(N+3)/4,256,0,stream>>>(rowptr, eidx, src, esc, v, agg, N);
    gemm128<EPI_RELU_RES,true,false,true><<<gN,256,0,stream>>>(agg, wob, feat, N,
        z, nullptr, nullptr, nullptr, feat);

    // ---- readout ----
    readout<<<(BT+255)/256,256,0,stream>>>(target_idx, meta_node_id, feat, p1mn,
        base, acc, d_out, (b==NB-1) ? 1 : 0, invNB, BT, dflag);
  }
}

// Round 6
// 1018.720 us; speedup vs baseline: 2.0215x; 1.4368x over previous
//
#include <hip/hip_runtime.h>
#include <hip/hip_bf16.h>

#define DD   128
#define HH   8

typedef short bf16x8 __attribute__((ext_vector_type(8)));
typedef float f32x4  __attribute__((ext_vector_type(4)));

__device__ __forceinline__ float b2f(unsigned short v){
  union { unsigned int u; float f; } x; x.u = ((unsigned int)v) << 16; return x.f;
}
__device__ __forceinline__ unsigned short f2b(float f){
  __hip_bfloat16 h = __float2bfloat16(f);
  return *(unsigned short*)&h;
}
struct __align__(8) us4 { unsigned short x,y,z,w; };
struct __align__(4) us2 { unsigned short x,y; };

__device__ __forceinline__ float gld(const void* p, size_t i, bool f32){
  if (f32) return ((const float*)p)[i];
  return b2f(((const unsigned short*)p)[i]);
}

// Detect input float dtype. emb ~ N(0,1)*0.05. If f32, odd ushorts are mantissa
// garbage -> huge "bf16" values. flag=1 -> inputs are f32.
__global__ __launch_bounds__(64) void k_detect(const unsigned short* __restrict__ emb,
                                               int* __restrict__ flag){
  int t = threadIdx.x;
  float m = 0.f;
  for (int i=t; i<128; i+=64){
    float x = fabsf(b2f(emb[i]));
    if (x < 1e30f) m = fmaxf(m, x);
  }
#pragma unroll
  for (int s=1;s<64;s<<=1) m = fmaxf(m, __shfl_xor(m, s, 64));
  if (t==0) *flag = (m > 1e4f) ? 1 : 0;
}

// stage = bf16( W[bo + k*128 + n] ) stored TRANSPOSED as stage[n*128 + k]
// (k-contiguous per output column n -> MFMA B-fragments are ds_read_b128).
__global__ __launch_bounds__(256) void w_repack(
    const void* __restrict__ W, unsigned short* __restrict__ stage,
    size_t bo, const int* __restrict__ dflag)
{
  const bool wf32 = (*dflag) != 0;
  int i = blockIdx.x*256 + threadIdx.x;
  if (i >= DD*DD) return;
  int k = i >> 7, n = i & 127;
  float x;
  if (wf32) x = ((const float*)W)[bo + i];
  else      x = b2f(((const unsigned short*)W)[bo + i]);
  stage[n*DD + k] = f2b(x);
}

enum { EPI_STORE=0, EPI_SCALE_CONST=1, EPI_SCALE_GATHER=2, EPI_RELU=3, EPI_RELU_RES=4 };

#define APAD 136   // 128 + 8 bf16: breaks stride-256B bank aliasing
#define CPAD 132   // f32 row pad for epilogue repack

// C[M,128] = epi( prologue(A)[M,128] @ B[128,128] ), B bf16 TRANSPOSED ([n][k]).
// MFMA 16x16x32 bf16. Block: 256 thr = 4 waves; 64 rows x 128 cols per block.
template<int EPI, bool NORM, bool INB, bool OUTB>
__global__ __launch_bounds__(256) void gemm128m(
    const void* __restrict__ Av, const unsigned short* __restrict__ Bt,
    void* __restrict__ Cv, int M,
    const float* __restrict__ z, const float* __restrict__ svec,
    const float* __restrict__ P2, const int* __restrict__ gidx,
    const unsigned short* __restrict__ Rb)
{
  __shared__ unsigned short Asb[64*APAD];    // [row][k] bf16
  __shared__ unsigned short Btb[128*APAD];   // [n][k] bf16; aliased by C f32 later
  const int tid = threadIdx.x;
  const int wave = tid >> 6, lane = tid & 63;
  const int row0 = blockIdx.x * 64;

  // ---- stage A: thread handles row=tid>>2, 32 cols at (tid&3)*32 ----
  {
    int r = tid >> 2, cb = (tid & 3) * 32;
    int gr = row0 + r;
    if (INB){
      const unsigned short* Ab = (const unsigned short*)Av;
#pragma unroll
      for (int j=0;j<4;j++){
        int c = cb + j*8;
        uint4 raw = make_uint4(0,0,0,0);
        if (gr < M) raw = *(const uint4*)(Ab + (size_t)gr*DD + c);
        *(uint4*)&Asb[r*APAD + c] = raw;
      }
    } else {
      const float* Af = (const float*)Av;
#pragma unroll
      for (int j=0;j<8;j++){
        int c = cb + j*4;
        float4 val = make_float4(0.f,0.f,0.f,0.f);
        if (gr < M){
          val = *(const float4*)(Af + (size_t)gr*DD + c);
          if (NORM){
            float s = 1.0f / (z[(size_t)gr*HH + (c>>4)] + 1e-9f);
            val.x*=s; val.y*=s; val.z*=s; val.w*=s;
          }
        }
        us4 o; o.x=f2b(val.x); o.y=f2b(val.y); o.z=f2b(val.z); o.w=f2b(val.w);
        *(us4*)&Asb[r*APAD + c] = o;
      }
    }
  }
  // ---- stage Bt (straight copy, already transposed in global) ----
  {
    int n = tid >> 1, k0s = (tid & 1) * 64;
#pragma unroll
    for (int j=0;j<8;j++){
      uint4 raw = *(const uint4*)(Bt + (size_t)n*DD + k0s + j*8);
      *(uint4*)&Btb[n*APAD + k0s + j*8] = raw;
    }
  }
  __syncthreads();

  // ---- MFMA K-loop: wave owns rows [wave*16, wave*16+16), all 128 cols ----
  f32x4 acc[8];
#pragma unroll
  for (int t=0;t<8;t++) acc[t] = (f32x4){0.f,0.f,0.f,0.f};
  const int am = (lane & 15), kq = (lane >> 4) * 8;
#pragma unroll
  for (int k0=0;k0<128;k0+=32){
    bf16x8 a = *(bf16x8*)&Asb[(wave*16 + am)*APAD + k0 + kq];
#pragma unroll
    for (int t=0;t<8;t++){
      bf16x8 b = *(bf16x8*)&Btb[(t*16 + am)*APAD + k0 + kq];
      acc[t] = __builtin_amdgcn_mfma_f32_16x16x32_bf16(a, b, acc[t], 0,0,0);
    }
  }
  __syncthreads();            // all Btb reads done before aliasing as C
  float* Cls = (float*)Btb;   // [64][CPAD] f32
  {
    int rr = wave*16 + (lane>>4)*4;
    int cc = lane & 15;
#pragma unroll
    for (int t=0;t<8;t++)
#pragma unroll
      for (int r=0;r<4;r++)
        Cls[(rr + r)*CPAD + t*16 + cc] = acc[t][r];
  }
  __syncthreads();

  // ---- epilogue: thread handles row=tid>>2, 32 cols at (tid&3)*32 ----
  {
    int r = tid >> 2, cb = (tid & 3) * 32;
    int gr = row0 + r;
    if (gr < M){
#pragma unroll
      for (int j=0;j<8;j++){
        int c = cb + j*4;
        float4 o = *(float4*)&Cls[r*CPAD + c];
        if (EPI == EPI_SCALE_CONST){
          o.x*=svec[c+0]; o.y*=svec[c+1]; o.z*=svec[c+2]; o.w*=svec[c+3];
        } else if (EPI == EPI_SCALE_GATHER){
          int g = gidx[gr];
          const float* p = P2 + (size_t)g*DD + c;
          o.x*=(svec[c+0]+p[0]); o.y*=(svec[c+1]+p[1]);
          o.z*=(svec[c+2]+p[2]); o.w*=(svec[c+3]+p[3]);
        } else if (EPI == EPI_RELU){
          o.x=fmaxf(o.x,0.f); o.y=fmaxf(o.y,0.f); o.z=fmaxf(o.z,0.f); o.w=fmaxf(o.w,0.f);
        } else if (EPI == EPI_RELU_RES){
          us4 rb = *(const us4*)(Rb + (size_t)gr*DD + c);
          o.x=fmaxf(o.x,0.f)+b2f(rb.x); o.y=fmaxf(o.y,0.f)+b2f(rb.y);
          o.z=fmaxf(o.z,0.f)+b2f(rb.z); o.w=fmaxf(o.w,0.f)+b2f(rb.w);
        }
        if (OUTB){
          us4 ob; ob.x=f2b(o.x); ob.y=f2b(o.y); ob.z=f2b(o.z); ob.w=f2b(o.w);
          *(us4*)((unsigned short*)Cv + (size_t)gr*DD + c) = ob;
        } else {
          *(float4*)((float*)Cv + (size_t)gr*DD + c) = o;
        }
      }
    }
  }
}

// Static param-name graph -> base params. base: [0..7]=tw,[8..15]=n1,[16..23]=e1,
// [24..151]=n2,[152..279]=e2
__global__ __launch_bounds__(256) void k_static(
    const void* __restrict__ emb, const int* __restrict__ svals,
    const int* __restrict__ ssrc, const int* __restrict__ sdst,
    const void* __restrict__ u, const void* __restrict__ W2,
    const void* __restrict__ W1, float* __restrict__ base, int nsrc,
    const int* __restrict__ dflag)
{
  __shared__ float sagg[15][128];
  __shared__ float ssc[15][16];
  __shared__ float sww[15][16];
  const bool wf32 = (*dflag) != 0;
  const int t = threadIdx.x;
  for (int i=t;i<15*128;i+=256) ((float*)sagg)[i]=0.f;
  __syncthreads();
  if (t < 128){
    for (int i=0;i<nsrc;i++){
      int row = sdst[i]; int vr = svals[ssrc[i]];
      sagg[row][t] += gld(emb, (size_t)vr*DD + t, wf32);
    }
  }
  __syncthreads();
  if (t < 240){
    int n = t>>4, l = t&15;
    float a=0.f;
    for (int d=0;d<128;d++) a += sagg[n][d]*gld(u, l*128+d, wf32);
    ssc[n][l] = a * 0.08838834764831845f;
  }
  __syncthreads();
  if (t < 15){
    float mx=-1e30f;
    for (int l=0;l<16;l++) mx = fmaxf(mx, ssc[t][l]);
    float s=0.f;
    for (int l=0;l<16;l++){ float e=__expf(ssc[t][l]-mx); sww[t][l]=e; s+=e; }
    float inv = 1.f/s;
    for (int l=0;l<16;l++) sww[t][l]*=inv;
  }
  __syncthreads();
  if (t < 8){
    float a=0.f,b=0.f,c=0.f;
    for (int l=0;l<16;l++){
      float wv = gld(W1, l*8+t, wf32);
      a += sww[0][l]*wv; b += sww[3][l]*wv; c += sww[9][l]*wv;
    }
    base[t]=a; base[8+t]=b; base[16+t]=c;
  }
  if (t < 128){
    float a=0.f,b=0.f;
    for (int l=0;l<16;l++){
      float wv = gld(W2, l*128+t, wf32);
      a += sww[6][l]*wv; b += sww[12][l]*wv;
    }
    base[24+t]=a; base[152+t]=b;
  }
}

template<bool OUTB>
__global__ __launch_bounds__(256) void gather_rows(
    const void* __restrict__ emb, const int* __restrict__ vals,
    void* __restrict__ dstv, int n, const int* __restrict__ dflag)
{
  const bool wf32 = (*dflag) != 0;
  int i = blockIdx.x*256 + threadIdx.x;
  if (i >= n*16) return;
  int r = i>>4, c = (i&15)*8;
  int vr = vals[r];
  float vb[8];
  if (wf32){
    float4 f0 = *(const float4*)((const float*)emb + (size_t)vr*DD + c);
    float4 f1 = *(const float4*)((const float*)emb + (size_t)vr*DD + c + 4);
    vb[0]=f0.x; vb[1]=f0.y; vb[2]=f0.z; vb[3]=f0.w;
    vb[4]=f1.x; vb[5]=f1.y; vb[6]=f1.z; vb[7]=f1.w;
  } else {
    uint4 raw = *(const uint4*)((const unsigned short*)emb + (size_t)vr*DD + c);
    const unsigned short* hw = (const unsigned short*)&raw;
#pragma unroll
    for (int j=0;j<8;j++) vb[j] = b2f(hw[j]);
  }
  if (OUTB){
    unsigned short* d = (unsigned short*)dstv + (size_t)r*DD + c;
    us4 o0, o1;
    o0.x=f2b(vb[0]); o0.y=f2b(vb[1]); o0.z=f2b(vb[2]); o0.w=f2b(vb[3]);
    o1.x=f2b(vb[4]); o1.y=f2b(vb[5]); o1.z=f2b(vb[6]); o1.w=f2b(vb[7]);
    *(us4*)d = o0; *(us4*)(d+4) = o1;
  } else {
    float* d = (float*)dstv + (size_t)r*DD + c;
    *(float4*)d     = make_float4(vb[0],vb[1],vb[2],vb[3]);
    *(float4*)(d+4) = make_float4(vb[4],vb[5],vb[6],vb[7]);
  }
}

__global__ __launch_bounds__(256) void zerof(float* __restrict__ p, long n4){
  long i = (long)blockIdx.x*256 + threadIdx.x;
  if (i < n4) ((float4*)p)[i] = make_float4(0.f,0.f,0.f,0.f);
}
__global__ __launch_bounds__(256) void zeroi(int* __restrict__ p, int n){
  int i = blockIdx.x*256 + threadIdx.x;
  if (i < n) p[i] = 0;
}

// ---------------- CSR build (by dst) ----------------
__global__ __launch_bounds__(256) void k_hist(const int* __restrict__ dst,
                                              int* __restrict__ deg, int E){
  int i = blockIdx.x*256 + threadIdx.x;
  if (i < E) atomicAdd(&deg[dst[i]], 1);
}

__global__ __launch_bounds__(256) void k_scan1(const int* __restrict__ deg,
                                               int* __restrict__ rowptr,
                                               int* __restrict__ bsum, int n){
  __shared__ int ls[256];
  int b = blockIdx.x, t = threadIdx.x;
  int base = b*1024 + t*4;
  int v0 = (base+0<n)?deg[base+0]:0;
  int v1 = (base+1<n)?deg[base+1]:0;
  int v2 = (base+2<n)?deg[base+2]:0;
  int v3 = (base+3<n)?deg[base+3]:0;
  int tsum = v0+v1+v2+v3;
  ls[t] = tsum; __syncthreads();
  for (int o=1;o<256;o<<=1){
    int x = (t>=o) ? ls[t-o] : 0;
    __syncthreads();
    ls[t] += x;
    __syncthreads();
  }
  int excl = ls[t]-tsum;
  if (t==255) bsum[b] = ls[255];
  if (base+0<n) rowptr[base+0]=excl;
  if (base+1<n) rowptr[base+1]=excl+v0;
  if (base+2<n) rowptr[base+2]=excl+v0+v1;
  if (base+3<n) rowptr[base+3]=excl+v0+v1+v2;
}

__global__ __launch_bounds__(64) void k_scan2(int* __restrict__ bsum, int nb,
                                              int* __restrict__ rowptr, int n){
  if (threadIdx.x==0){
    int run = 0;
    for (int b=0;b<nb;b++){ int x = bsum[b]; bsum[b] = run; run += x; }
    rowptr[n] = run;
  }
}

__global__ __launch_bounds__(256) void k_scan3(int* __restrict__ rowptr,
                                               const int* __restrict__ bsum,
                                               int* __restrict__ cursor, int n){
  int i = blockIdx.x*256 + threadIdx.x;
  if (i < n){
    int r = rowptr[i] + bsum[i>>10];
    rowptr[i] = r;
    cursor[i] = r;
  }
}

__global__ __launch_bounds__(256) void k_scatter(const int* __restrict__ dst,
                                                 int* __restrict__ cursor,
                                                 int* __restrict__ eidx, int E){
  int e = blockIdx.x*256 + threadIdx.x;
  if (e < E){
    int p = atomicAdd(&cursor[dst[e]], 1);
    eidx[p] = e;
  }
}

// ---------------- meta-graph edges (tiny, atomic version) ----------------
__global__ __launch_bounds__(256) void edge_meta(
    const int* __restrict__ src, const int* __restrict__ dst,
    const unsigned short* __restrict__ qm, const unsigned short* __restrict__ kfm,
    const unsigned short* __restrict__ vm,
    const float* __restrict__ base, unsigned short* __restrict__ mef,
    float* __restrict__ z, float* __restrict__ agg, int E)
{
  int e = blockIdx.x*4 + (threadIdx.x>>6);
  if (e >= E) return;
  int lane = threadIdx.x & 63;
  int s = src[e], d = dst[e];
  const float* be2 = base+152; const float* be1 = base+16; const float* bn1 = base+8;
  size_t so=(size_t)s*DD, dq=(size_t)d*DD, eo=(size_t)e*DD;
  float ke0 = b2f(kfm[so+lane])    * be2[lane];
  float ke1 = b2f(kfm[so+64+lane]) * be2[64+lane];
  mef[eo+lane]=f2b(ke0); mef[eo+64+lane]=f2b(ke1);
  float p0 = b2f(qm[dq+lane])*ke0, p1 = b2f(qm[dq+64+lane])*ke1;
#pragma unroll
  for (int m=1;m<16;m<<=1){ p0 += __shfl_xor(p0,m,64); p1 += __shfl_xor(p1,m,64); }
  int h0 = lane>>4, h1 = h0+4;
  float s0 = p0*0.25f + be1[h0] + bn1[h0];
  float s1 = p1*0.25f + be1[h1] + bn1[h1];
  float e0 = __expf(s0), e1 = __expf(s1);
  if ((lane&15)==0){ atomicAdd(&z[(size_t)d*HH+h0], e0); atomicAdd(&z[(size_t)d*HH+h1], e1); }
  atomicAdd(&agg[dq+lane],    e0*b2f(vm[so+lane]));
  atomicAdd(&agg[dq+64+lane], e1*b2f(vm[so+64+lane]));
}

// ---------------- big-graph: fused scores+softmax-weighted agg ----------------
// One wave per dst node. Lane holds element pair (2*lane, 2*lane+1); head = lane>>3.
// No esc buffer: exp(score) is consumed in-wave. Non-atomic z/agg stores.
__global__ __launch_bounds__(256) void edge_fused(
    const int* __restrict__ rowptr, const int* __restrict__ eidx,
    const int* __restrict__ src, const int* __restrict__ meid,
    const int* __restrict__ mnid,
    const unsigned short* __restrict__ q, const unsigned short* __restrict__ kf,
    const unsigned short* __restrict__ v,
    const unsigned short* __restrict__ p2me, const unsigned short* __restrict__ p1me,
    const float* __restrict__ p1mn, const float* __restrict__ base,
    float* __restrict__ z, float* __restrict__ agg, int N)
{
  int d = blockIdx.x*4 + (threadIdx.x>>6);
  if (d >= N) return;
  int lane = threadIdx.x & 63;
  int c2 = lane*2;
  int h = lane>>3;
  size_t dq = (size_t)d*DD;
  const float* be2 = base+152; const float* be1 = base+16; const float* bn1 = base+8;
  us2 qp = *(const us2*)(q + dq + c2);
  float qa = b2f(qp.x), qb = b2f(qp.y);
  float w2a = be2[c2], w2b = be2[c2+1];
  int mn = mnid[d];
  float bias = be1[h] + bn1[h] + p1mn[(size_t)mn*HH + h];
  float zh = 0.f, a0 = 0.f, a1 = 0.f;
  int i0 = rowptr[d], i1 = rowptr[d+1];
  for (int i=i0; i<i1; i++){
    int e = eidx[i];
    int s = src[e], me = meid[e];
    size_t so = (size_t)s*DD, mo = (size_t)me*DD;
    us2 kp = *(const us2*)(kf + so + c2);
    us2 pp = *(const us2*)(p2me + mo + c2);
    float kea = b2f(kp.x)*(w2a + b2f(pp.x));
    float keb = b2f(kp.y)*(w2b + b2f(pp.y));
    float p = qa*kea + qb*keb;
    p += __shfl_xor(p,1,64); p += __shfl_xor(p,2,64); p += __shfl_xor(p,4,64);
    float score = p*0.25f + bias + b2f(p1me[(size_t)me*HH + h]);
    float ex = __expf(score);
    zh += ex;
    us2 vp = *(const us2*)(v + so + c2);
    a0 += ex*b2f(vp.x);
    a1 += ex*b2f(vp.y);
  }
  if ((lane&7)==0) z[(size_t)d*HH + h] = zh;
  *(float2*)(agg + dq + c2) = make_float2(a0, a1);
}

template<bool XB, bool PB>
__global__ __launch_bounds__(128) void learner(
    const void* __restrict__ X, const void* __restrict__ u,
    const void* __restrict__ W2, const void* __restrict__ W1,
    void* __restrict__ p2, void* __restrict__ p1, const int* __restrict__ dflag)
{
  __shared__ float sX[128];
  __shared__ float st[16];
  __shared__ float sw[16];
  const bool wf32 = (*dflag) != 0;
  const int m = blockIdx.x, t = threadIdx.x;
  if (XB) sX[t] = b2f(((const unsigned short*)X)[(size_t)m*DD + t]);
  else    sX[t] = ((const float*)X)[(size_t)m*DD + t];
  __syncthreads();
  int l = t>>3, j = t&7;
  float part = 0.f;
  for (int d=j*16; d<j*16+16; d++) part += sX[d]*gld(u, l*128+d, wf32);
  part += __shfl_xor(part,1,64); part += __shfl_xor(part,2,64); part += __shfl_xor(part,4,64);
  if (j==0) st[l] = part * 0.08838834764831845f;
  __syncthreads();
  float mx=-1e30f;
  for (int i=0;i<16;i++) mx = fmaxf(mx, st[i]);
  float ssum=0.f;
  for (int i=0;i<16;i++) ssum += __expf(st[i]-mx);
  float inv = 1.f/ssum;
  if (t<16) sw[t] = __expf(st[t]-mx)*inv;
  __syncthreads();
  float a=0.f;
  for (int i=0;i<16;i++) a += sw[i]*gld(W2, i*128+t, wf32);
  if (PB) ((unsigned short*)p2)[(size_t)m*DD+t] = f2b(a);
  else    ((float*)p2)[(size_t)m*DD+t] = a;
  if (t<8){
    float bb=0.f;
    for (int i=0;i<16;i++) bb += sw[i]*gld(W1, i*8+t, wf32);
    if (PB) ((unsigned short*)p1)[(size_t)m*HH+t] = f2b(bb);
    else    ((float*)p1)[(size_t)m*HH+t] = bb;
  }
}

__global__ __launch_bounds__(256) void resadd(float* __restrict__ a, const float* __restrict__ b, int n){
  int i = blockIdx.x*256 + threadIdx.x;
  if (i < n) a[i] += b[i];
}

__global__ __launch_bounds__(256) void readout(
    const int* __restrict__ tgt, const int* __restrict__ mnid,
    const unsigned short* __restrict__ featb, const float* __restrict__ p1mn,
    const float* __restrict__ base, float* __restrict__ acc,
    void* __restrict__ out, int last, float invNB, int BT,
    const int* __restrict__ dflag)
{
  int t = blockIdx.x*256 + threadIdx.x;
  if (t >= BT) return;
  int idx = tgt[t]; int mn = mnid[idx];
  float logit = 0.f;
  for (int h=0;h<8;h++){
    float tw = base[h] + p1mn[(size_t)mn*HH + h];
    float srow = 0.f;
    for (int k=0;k<16;k++) srow += b2f(featb[(size_t)idx*DD + h*16 + k]);
    logit += tw*srow;
  }
  if (!last) acc[t] = logit;
  else {
    float r = (acc[t] + logit) * invNB;
    if ((*dflag) != 0) ((float*)out)[t] = r;
    else ((__hip_bfloat16*)out)[t] = __float2bfloat16(r);
  }
}

extern "C" void kernel_launch(void* const* d_in, const int* in_sizes, int n_in,
                              void* d_out, int out_size, void* d_ws, size_t ws_size,
                              hipStream_t stream) {
  const void* emb   = d_in[0];
  const void* u     = d_in[1];
  const void* W2lat = d_in[2];
  const void* W1lat = d_in[3];
  const void* Wmat[8] = { d_in[4], d_in[5], d_in[6], d_in[7],
                          d_in[8], d_in[9], d_in[10], d_in[11] };
  const int* node_vals      = (const int*)d_in[12];
  const int* meta_node_vals = (const int*)d_in[13];
  const int* src            = (const int*)d_in[14];
  const int* dst            = (const int*)d_in[15];
  const int* meta_src       = (const int*)d_in[16];
  const int* meta_dst       = (const int*)d_in[17];
  const int* meta_node_id   = (const int*)d_in[18];
  const int* meta_edge_id   = (const int*)d_in[19];
  const int* target_idx     = (const int*)d_in[20];
  const int* static_vals    = (const int*)d_in[21];
  const int* static_src     = (const int*)d_in[22];
  const int* static_dst     = (const int*)d_in[23];

  const int N  = in_sizes[12];
  const int MN = in_sizes[13];
  const int E  = in_sizes[14];
  const int ME = in_sizes[16];
  const int BT = in_sizes[20];
  const int NSRC = in_sizes[22];
  const int NB = in_sizes[8] / (DD*DD);

  // Workspace (~164 MB for N=100K,E=800K; proven budget >= ~194 MB)
  float* ws = (float*)d_ws;
  size_t off = 0;
  auto allocf = [&](size_t n){ float* p = ws + off; off += n; return p; };
  auto allocb = [&](size_t n){ unsigned short* p = (unsigned short*)(ws + off); off += (n+1)/2; return p; };
  auto alloci = [&](size_t n){ int* p = (int*)(ws + off); off += n; return p; };
  int*            dflag = (int*)ws; off += 4;
  unsigned short* feat  = allocb((size_t)N*DD);
  unsigned short* q     = allocb((size_t)N*DD);
  unsigned short* kf    = allocb((size_t)N*DD);
  unsigned short* v     = allocb((size_t)N*DD);
  float*          agg   = allocf((size_t)N*DD);   // dedicated f32 (q/kf/v live in fused kernel)
  float*          z     = allocf((size_t)N*HH);
  float*          meta_feat= allocf((size_t)MN*DD);
  float*          agg_m = allocf((size_t)MN*DD);  // z_m contiguous follows
  float*          z_m   = allocf((size_t)MN*HH);
  unsigned short* q_m   = allocb((size_t)MN*DD);
  unsigned short* kf_m  = allocb((size_t)MN*DD);
  unsigned short* v_m   = allocb((size_t)MN*DD);
  float*          meta_out = allocf((size_t)MN*DD);
  unsigned short* mef   = allocb((size_t)ME*DD);
  float*          p2mn  = allocf((size_t)MN*DD);
  float*          p1mn  = allocf((size_t)MN*HH);
  unsigned short* p2me  = allocb((size_t)ME*DD);
  unsigned short* p1me  = allocb((size_t)ME*HH);
  float*          base  = allocf(280);
  float*          acc   = allocf((size_t)BT);
  unsigned short* wstage= allocb((size_t)8*DD*DD);  // transposed bf16 weights
  int*            rowptr= alloci((size_t)N+1);
  int*            cursor= alloci((size_t)N);
  int*            deg   = alloci((size_t)N);
  int*            eidx  = alloci((size_t)E);
  const int nb_scan = (N + 1023)/1024;
  int*            bsum  = alloci((size_t)nb_scan);
  (void)ws_size; (void)n_in; (void)out_size;

  const float* base_n2 = base + 24;

  k_detect<<<1,64,0,stream>>>((const unsigned short*)emb, dflag);
  k_static<<<1,256,0,stream>>>(emb, static_vals, static_src, static_dst,
                               u, W2lat, W1lat, base, NSRC, dflag);
  gather_rows<true ><<<(N*16+255)/256,256,0,stream>>>(emb, node_vals, feat, N, dflag);
  gather_rows<false><<<(MN*16+255)/256,256,0,stream>>>(emb, meta_node_vals, meta_feat, MN, dflag);

  // ---- CSR build (by dst), once per call ----
  zeroi<<<(N+255)/256,256,0,stream>>>(deg, N);
  k_hist<<<(E+255)/256,256,0,stream>>>(dst, deg, E);
  k_scan1<<<nb_scan,256,0,stream>>>(deg, rowptr, bsum, N);
  k_scan2<<<1,64,0,stream>>>(bsum, nb_scan, rowptr, N);
  k_scan3<<<(N+255)/256,256,0,stream>>>(rowptr, bsum, cursor, N);
  k_scatter<<<(E+255)/256,256,0,stream>>>(dst, cursor, eidx, E);

  const int gm = (MN+63)/64;
  const int gN = (N+63)/64;
  const long nz_meta = ((long)MN*DD + (long)MN*HH)/4;
  const float invNB = 1.0f/(float)NB;

  for (int b=0;b<NB;b++){
    const size_t bo = (size_t)b*DD*DD;
    for (int wi=0; wi<8; wi++)
      w_repack<<<64,256,0,stream>>>(Wmat[wi], wstage + (size_t)wi*DD*DD, bo, dflag);
    const unsigned short* wq_m = wstage + 0*DD*DD;
    const unsigned short* wk_m = wstage + 1*DD*DD;
    const unsigned short* wv_m = wstage + 2*DD*DD;
    const unsigned short* wo_m = wstage + 3*DD*DD;
    const unsigned short* wqb  = wstage + 4*DD*DD;
    const unsigned short* wkb  = wstage + 5*DD*DD;
    const unsigned short* wvb  = wstage + 6*DD*DD;
    const unsigned short* wob  = wstage + 7*DD*DD;

    // ---- meta conv (broadcast base params) ----
    gemm128m<EPI_SCALE_CONST,false,false,true><<<gm,256,0,stream>>>(meta_feat, wq_m, q_m, MN,
        nullptr, base_n2, nullptr, nullptr, nullptr);
    gemm128m<EPI_STORE,false,false,true><<<gm,256,0,stream>>>(meta_feat, wk_m, kf_m, MN,
        nullptr, nullptr, nullptr, nullptr, nullptr);
    gemm128m<EPI_STORE,false,false,true><<<gm,256,0,stream>>>(meta_feat, wv_m, v_m, MN,
        nullptr, nullptr, nullptr, nullptr, nullptr);
    zerof<<<(int)((nz_meta+255)/256),256,0,stream>>>(agg_m, nz_meta);
    edge_meta<<<(ME+3)/4,256,0,stream>>>(meta_src, meta_dst, q_m, kf_m, v_m,
        base, mef, z_m, agg_m, ME);
    gemm128m<EPI_RELU,true,false,false><<<gm,256,0,stream>>>(agg_m, wo_m, meta_out, MN,
        z_m, nullptr, nullptr, nullptr, nullptr);

    // ---- meta learners (pre-residual conv outputs) ----
    learner<false,false><<<MN,128,0,stream>>>(meta_out, u, W2lat, W1lat, p2mn, p1mn, dflag);
    learner<true ,true ><<<ME,128,0,stream>>>(mef,      u, W2lat, W1lat, p2me, p1me, dflag);
    resadd<<<(MN*DD+255)/256,256,0,stream>>>(meta_feat, meta_out, MN*DD);

    // ---- big conv ----
    gemm128m<EPI_SCALE_GATHER,false,true,true><<<gN,256,0,stream>>>(feat, wqb, q, N,
        nullptr, base_n2, p2mn, meta_node_id, nullptr);
    gemm128m<EPI_STORE,false,true,true><<<gN,256,0,stream>>>(feat, wkb, kf, N,
        nullptr, nullptr, nullptr, nullptr, nullptr);
    gemm128m<EPI_STORE,false,true,true><<<gN,256,0,stream>>>(feat, wvb, v, N,
        nullptr, nullptr, nullptr, nullptr, nullptr);
    edge_fused<<<(N+3)/4,256,0,stream>>>(rowptr, eidx, src, meta_edge_id,
        meta_node_id, q, kf, v, p2me, p1me, p1mn, base, z, agg, N);
    gemm128m<EPI_RELU_RES,true,false,true><<<gN,256,0,stream>>>(agg, wob, feat, N,
        z, nullptr, nullptr, nullptr, feat);

    // ---- readout ----
    readout<<<(BT+255)/256,256,0,stream>>>(target_idx, meta_node_id, feat, p1mn,
        base, acc, d_out, (b==NB-1) ? 1 : 0, invNB, BT, dflag);
  }
}

// Round 7
// 888.023 us; speedup vs baseline: 2.3190x; 1.1472x over previous
//
#include <hip/hip_runtime.h>
#include <hip/hip_bf16.h>

#define DD   128
#define HH   8

typedef short bf16x8 __attribute__((ext_vector_type(8)));
typedef float f32x4  __attribute__((ext_vector_type(4)));

__device__ __forceinline__ float b2f(unsigned short v){
  union { unsigned int u; float f; } x; x.u = ((unsigned int)v) << 16; return x.f;
}
__device__ __forceinline__ unsigned short f2b(float f){
  __hip_bfloat16 h = __float2bfloat16(f);
  return *(unsigned short*)&h;
}
struct __align__(8) us4 { unsigned short x,y,z,w; };
struct __align__(4) us2 { unsigned short x,y; };

__device__ __forceinline__ float gld(const void* p, size_t i, bool f32){
  if (f32) return ((const float*)p)[i];
  return b2f(((const unsigned short*)p)[i]);
}

// Detect input float dtype. emb ~ N(0,1)*0.05. If f32, odd ushorts are mantissa
// garbage -> huge "bf16" values. flag=1 -> inputs are f32.
__global__ __launch_bounds__(64) void k_detect(const unsigned short* __restrict__ emb,
                                               int* __restrict__ flag){
  int t = threadIdx.x;
  float m = 0.f;
  for (int i=t; i<128; i+=64){
    float x = fabsf(b2f(emb[i]));
    if (x < 1e30f) m = fmaxf(m, x);
  }
#pragma unroll
  for (int s=1;s<64;s<<=1) m = fmaxf(m, __shfl_xor(m, s, 64));
  if (t==0) *flag = (m > 1e4f) ? 1 : 0;
}

// All 8 weight blocks -> bf16 TRANSPOSED staging ([n][k]) in one launch.
struct WPtrs { const void* p[8]; };
__global__ __launch_bounds__(256) void w_repack8(
    WPtrs W, unsigned short* __restrict__ stage,
    size_t bo, const int* __restrict__ dflag)
{
  const bool wf32 = (*dflag) != 0;
  int mat = blockIdx.x >> 6;
  int i = (blockIdx.x & 63)*256 + threadIdx.x;
  int k = i >> 7, n = i & 127;
  float x;
  if (wf32) x = ((const float*)W.p[mat])[bo + i];
  else      x = b2f(((const unsigned short*)W.p[mat])[bo + i]);
  stage[(size_t)mat*DD*DD + n*DD + k] = f2b(x);
}

enum { EPI_STORE=0, EPI_SCALE_CONST=1, EPI_SCALE_GATHER=2, EPI_RELU=3, EPI_RELU_RES=4 };

#define APAD 136   // 128 + 8 bf16: breaks stride-256B bank aliasing
#define CPAD 132   // f32 row pad for epilogue repack

// C[M,128] = epi( prologue(A)[M,128] @ B[128,128] ), B bf16 TRANSPOSED ([n][k]).
// MFMA 16x16x32 bf16. Block: 256 thr = 4 waves; 64 rows x 128 cols per block.
template<int EPI, bool NORM, bool INB, bool OUTB>
__global__ __launch_bounds__(256) void gemm128m(
    const void* __restrict__ Av, const unsigned short* __restrict__ Bt,
    void* __restrict__ Cv, int M,
    const float* __restrict__ z, const float* __restrict__ svec,
    const float* __restrict__ P2, const int* __restrict__ gidx,
    const unsigned short* __restrict__ Rb)
{
  __shared__ unsigned short Asb[64*APAD];    // [row][k] bf16
  __shared__ unsigned short Btb[128*APAD];   // [n][k] bf16; aliased by C f32 later
  const int tid = threadIdx.x;
  const int wave = tid >> 6, lane = tid & 63;
  const int row0 = blockIdx.x * 64;

  {
    int r = tid >> 2, cb = (tid & 3) * 32;
    int gr = row0 + r;
    if (INB){
      const unsigned short* Ab = (const unsigned short*)Av;
#pragma unroll
      for (int j=0;j<4;j++){
        int c = cb + j*8;
        uint4 raw = make_uint4(0,0,0,0);
        if (gr < M) raw = *(const uint4*)(Ab + (size_t)gr*DD + c);
        *(uint4*)&Asb[r*APAD + c] = raw;
      }
    } else {
      const float* Af = (const float*)Av;
#pragma unroll
      for (int j=0;j<8;j++){
        int c = cb + j*4;
        float4 val = make_float4(0.f,0.f,0.f,0.f);
        if (gr < M){
          val = *(const float4*)(Af + (size_t)gr*DD + c);
          if (NORM){
            float s = 1.0f / (z[(size_t)gr*HH + (c>>4)] + 1e-9f);
            val.x*=s; val.y*=s; val.z*=s; val.w*=s;
          }
        }
        us4 o; o.x=f2b(val.x); o.y=f2b(val.y); o.z=f2b(val.z); o.w=f2b(val.w);
        *(us4*)&Asb[r*APAD + c] = o;
      }
    }
  }
  {
    int n = tid >> 1, k0s = (tid & 1) * 64;
#pragma unroll
    for (int j=0;j<8;j++){
      uint4 raw = *(const uint4*)(Bt + (size_t)n*DD + k0s + j*8);
      *(uint4*)&Btb[n*APAD + k0s + j*8] = raw;
    }
  }
  __syncthreads();

  f32x4 acc[8];
#pragma unroll
  for (int t=0;t<8;t++) acc[t] = (f32x4){0.f,0.f,0.f,0.f};
  const int am = (lane & 15), kq = (lane >> 4) * 8;
#pragma unroll
  for (int k0=0;k0<128;k0+=32){
    bf16x8 a = *(bf16x8*)&Asb[(wave*16 + am)*APAD + k0 + kq];
#pragma unroll
    for (int t=0;t<8;t++){
      bf16x8 b = *(bf16x8*)&Btb[(t*16 + am)*APAD + k0 + kq];
      acc[t] = __builtin_amdgcn_mfma_f32_16x16x32_bf16(a, b, acc[t], 0,0,0);
    }
  }
  __syncthreads();
  float* Cls = (float*)Btb;   // [64][CPAD] f32
  {
    int rr = wave*16 + (lane>>4)*4;
    int cc = lane & 15;
#pragma unroll
    for (int t=0;t<8;t++)
#pragma unroll
      for (int r=0;r<4;r++)
        Cls[(rr + r)*CPAD + t*16 + cc] = acc[t][r];
  }
  __syncthreads();

  {
    int r = tid >> 2, cb = (tid & 3) * 32;
    int gr = row0 + r;
    if (gr < M){
#pragma unroll
      for (int j=0;j<8;j++){
        int c = cb + j*4;
        float4 o = *(float4*)&Cls[r*CPAD + c];
        if (EPI == EPI_SCALE_CONST){
          o.x*=svec[c+0]; o.y*=svec[c+1]; o.z*=svec[c+2]; o.w*=svec[c+3];
        } else if (EPI == EPI_SCALE_GATHER){
          int g = gidx[gr];
          const float* p = P2 + (size_t)g*DD + c;
          o.x*=(svec[c+0]+p[0]); o.y*=(svec[c+1]+p[1]);
          o.z*=(svec[c+2]+p[2]); o.w*=(svec[c+3]+p[3]);
        } else if (EPI == EPI_RELU){
          o.x=fmaxf(o.x,0.f); o.y=fmaxf(o.y,0.f); o.z=fmaxf(o.z,0.f); o.w=fmaxf(o.w,0.f);
        } else if (EPI == EPI_RELU_RES){
          us4 rb = *(const us4*)(Rb + (size_t)gr*DD + c);
          o.x=fmaxf(o.x,0.f)+b2f(rb.x); o.y=fmaxf(o.y,0.f)+b2f(rb.y);
          o.z=fmaxf(o.z,0.f)+b2f(rb.z); o.w=fmaxf(o.w,0.f)+b2f(rb.w);
        }
        if (OUTB){
          us4 ob; ob.x=f2b(o.x); ob.y=f2b(o.y); ob.z=f2b(o.z); ob.w=f2b(o.w);
          *(us4*)((unsigned short*)Cv + (size_t)gr*DD + c) = ob;
        } else {
          *(float4*)((float*)Cv + (size_t)gr*DD + c) = o;
        }
      }
    }
  }
}

// Fused Q/K/V gemm: stage A once, run 3 weight matrices through the same LDS.
// EPIQ applies to the Q output (SCALE_GATHER for big, SCALE_CONST for meta);
// K and V are plain bf16 stores.
template<int EPIQ, bool INB>
__global__ __launch_bounds__(256) void gemm_qkv(
    const void* __restrict__ Av,
    const unsigned short* __restrict__ Btq, const unsigned short* __restrict__ Btk,
    const unsigned short* __restrict__ Btv,
    unsigned short* __restrict__ Cq, unsigned short* __restrict__ Ck,
    unsigned short* __restrict__ Cvo, int M,
    const float* __restrict__ svec, const float* __restrict__ P2,
    const int* __restrict__ gidx)
{
  __shared__ unsigned short Asb[64*APAD];
  __shared__ unsigned short Btb[128*APAD];
  const int tid = threadIdx.x;
  const int wave = tid >> 6, lane = tid & 63;
  const int row0 = blockIdx.x * 64;

  // ---- stage A once ----
  {
    int r = tid >> 2, cb = (tid & 3) * 32;
    int gr = row0 + r;
    if (INB){
      const unsigned short* Ab = (const unsigned short*)Av;
#pragma unroll
      for (int j=0;j<4;j++){
        int c = cb + j*8;
        uint4 raw = make_uint4(0,0,0,0);
        if (gr < M) raw = *(const uint4*)(Ab + (size_t)gr*DD + c);
        *(uint4*)&Asb[r*APAD + c] = raw;
      }
    } else {
      const float* Af = (const float*)Av;
#pragma unroll
      for (int j=0;j<8;j++){
        int c = cb + j*4;
        float4 val = make_float4(0.f,0.f,0.f,0.f);
        if (gr < M) val = *(const float4*)(Af + (size_t)gr*DD + c);
        us4 o; o.x=f2b(val.x); o.y=f2b(val.y); o.z=f2b(val.z); o.w=f2b(val.w);
        *(us4*)&Asb[r*APAD + c] = o;
      }
    }
  }

  const unsigned short* Bts[3] = {Btq, Btk, Btv};
  unsigned short* Cs[3] = {Cq, Ck, Cvo};
  const int am = (lane & 15), kq = (lane >> 4) * 8;

  for (int ph=0; ph<3; ph++){
    // stage Bt[ph] (phase 0: A-stage above also pending; sync covers both)
    {
      int n = tid >> 1, k0s = (tid & 1) * 64;
      const unsigned short* Bt = Bts[ph];
#pragma unroll
      for (int j=0;j<8;j++){
        uint4 raw = *(const uint4*)(Bt + (size_t)n*DD + k0s + j*8);
        *(uint4*)&Btb[n*APAD + k0s + j*8] = raw;
      }
    }
    __syncthreads();
    f32x4 acc[8];
#pragma unroll
    for (int t=0;t<8;t++) acc[t] = (f32x4){0.f,0.f,0.f,0.f};
#pragma unroll
    for (int k0=0;k0<128;k0+=32){
      bf16x8 a = *(bf16x8*)&Asb[(wave*16 + am)*APAD + k0 + kq];
#pragma unroll
      for (int t=0;t<8;t++){
        bf16x8 b = *(bf16x8*)&Btb[(t*16 + am)*APAD + k0 + kq];
        acc[t] = __builtin_amdgcn_mfma_f32_16x16x32_bf16(a, b, acc[t], 0,0,0);
      }
    }
    __syncthreads();
    float* Cls = (float*)Btb;
    {
      int rr = wave*16 + (lane>>4)*4;
      int cc = lane & 15;
#pragma unroll
      for (int t=0;t<8;t++)
#pragma unroll
        for (int r=0;r<4;r++)
          Cls[(rr + r)*CPAD + t*16 + cc] = acc[t][r];
    }
    __syncthreads();
    {
      int r = tid >> 2, cb = (tid & 3) * 32;
      int gr = row0 + r;
      if (gr < M){
#pragma unroll
        for (int j=0;j<8;j++){
          int c = cb + j*4;
          float4 o = *(float4*)&Cls[r*CPAD + c];
          if (ph == 0){
            if (EPIQ == EPI_SCALE_GATHER){
              int g = gidx[gr];
              const float* p = P2 + (size_t)g*DD + c;
              o.x*=(svec[c+0]+p[0]); o.y*=(svec[c+1]+p[1]);
              o.z*=(svec[c+2]+p[2]); o.w*=(svec[c+3]+p[3]);
            } else { // SCALE_CONST
              o.x*=svec[c+0]; o.y*=svec[c+1]; o.z*=svec[c+2]; o.w*=svec[c+3];
            }
          }
          us4 ob; ob.x=f2b(o.x); ob.y=f2b(o.y); ob.z=f2b(o.z); ob.w=f2b(o.w);
          *(us4*)(Cs[ph] + (size_t)gr*DD + c) = ob;
        }
      }
    }
    __syncthreads();   // Cls (=Btb) reads done before next phase restages
  }
}

// Static param-name graph -> base params. base: [0..7]=tw,[8..15]=n1,[16..23]=e1,
// [24..151]=n2,[152..279]=e2
__global__ __launch_bounds__(256) void k_static(
    const void* __restrict__ emb, const int* __restrict__ svals,
    const int* __restrict__ ssrc, const int* __restrict__ sdst,
    const void* __restrict__ u, const void* __restrict__ W2,
    const void* __restrict__ W1, float* __restrict__ base, int nsrc,
    const int* __restrict__ dflag)
{
  __shared__ float sagg[15][128];
  __shared__ float ssc[15][16];
  __shared__ float sww[15][16];
  const bool wf32 = (*dflag) != 0;
  const int t = threadIdx.x;
  for (int i=t;i<15*128;i+=256) ((float*)sagg)[i]=0.f;
  __syncthreads();
  if (t < 128){
    for (int i=0;i<nsrc;i++){
      int row = sdst[i]; int vr = svals[ssrc[i]];
      sagg[row][t] += gld(emb, (size_t)vr*DD + t, wf32);
    }
  }
  __syncthreads();
  if (t < 240){
    int n = t>>4, l = t&15;
    float a=0.f;
    for (int d=0;d<128;d++) a += sagg[n][d]*gld(u, l*128+d, wf32);
    ssc[n][l] = a * 0.08838834764831845f;
  }
  __syncthreads();
  if (t < 15){
    float mx=-1e30f;
    for (int l=0;l<16;l++) mx = fmaxf(mx, ssc[t][l]);
    float s=0.f;
    for (int l=0;l<16;l++){ float e=__expf(ssc[t][l]-mx); sww[t][l]=e; s+=e; }
    float inv = 1.f/s;
    for (int l=0;l<16;l++) sww[t][l]*=inv;
  }
  __syncthreads();
  if (t < 8){
    float a=0.f,b=0.f,c=0.f;
    for (int l=0;l<16;l++){
      float wv = gld(W1, l*8+t, wf32);
      a += sww[0][l]*wv; b += sww[3][l]*wv; c += sww[9][l]*wv;
    }
    base[t]=a; base[8+t]=b; base[16+t]=c;
  }
  if (t < 128){
    float a=0.f,b=0.f;
    for (int l=0;l<16;l++){
      float wv = gld(W2, l*128+t, wf32);
      a += sww[6][l]*wv; b += sww[12][l]*wv;
    }
    base[24+t]=a; base[152+t]=b;
  }
}

template<bool OUTB>
__global__ __launch_bounds__(256) void gather_rows(
    const void* __restrict__ emb, const int* __restrict__ vals,
    void* __restrict__ dstv, int n, const int* __restrict__ dflag)
{
  const bool wf32 = (*dflag) != 0;
  int i = blockIdx.x*256 + threadIdx.x;
  if (i >= n*16) return;
  int r = i>>4, c = (i&15)*8;
  int vr = vals[r];
  float vb[8];
  if (wf32){
    float4 f0 = *(const float4*)((const float*)emb + (size_t)vr*DD + c);
    float4 f1 = *(const float4*)((const float*)emb + (size_t)vr*DD + c + 4);
    vb[0]=f0.x; vb[1]=f0.y; vb[2]=f0.z; vb[3]=f0.w;
    vb[4]=f1.x; vb[5]=f1.y; vb[6]=f1.z; vb[7]=f1.w;
  } else {
    uint4 raw = *(const uint4*)((const unsigned short*)emb + (size_t)vr*DD + c);
    const unsigned short* hw = (const unsigned short*)&raw;
#pragma unroll
    for (int j=0;j<8;j++) vb[j] = b2f(hw[j]);
  }
  if (OUTB){
    unsigned short* d = (unsigned short*)dstv + (size_t)r*DD + c;
    us4 o0, o1;
    o0.x=f2b(vb[0]); o0.y=f2b(vb[1]); o0.z=f2b(vb[2]); o0.w=f2b(vb[3]);
    o1.x=f2b(vb[4]); o1.y=f2b(vb[5]); o1.z=f2b(vb[6]); o1.w=f2b(vb[7]);
    *(us4*)d = o0; *(us4*)(d+4) = o1;
  } else {
    float* d = (float*)dstv + (size_t)r*DD + c;
    *(float4*)d     = make_float4(vb[0],vb[1],vb[2],vb[3]);
    *(float4*)(d+4) = make_float4(vb[4],vb[5],vb[6],vb[7]);
  }
}

__global__ __launch_bounds__(256) void zerof(float* __restrict__ p, long n4){
  long i = (long)blockIdx.x*256 + threadIdx.x;
  if (i < n4) ((float4*)p)[i] = make_float4(0.f,0.f,0.f,0.f);
}
__global__ __launch_bounds__(256) void zeroi(int* __restrict__ p, int n){
  int i = blockIdx.x*256 + threadIdx.x;
  if (i < n) p[i] = 0;
}

// ---------------- CSR build (by dst) ----------------
__global__ __launch_bounds__(256) void k_hist(const int* __restrict__ dst,
                                              int* __restrict__ deg, int E){
  int i = blockIdx.x*256 + threadIdx.x;
  if (i < E) atomicAdd(&deg[dst[i]], 1);
}

__global__ __launch_bounds__(256) void k_scan1(const int* __restrict__ deg,
                                               int* __restrict__ rowptr,
                                               int* __restrict__ bsum, int n){
  __shared__ int ls[256];
  int b = blockIdx.x, t = threadIdx.x;
  int base = b*1024 + t*4;
  int v0 = (base+0<n)?deg[base+0]:0;
  int v1 = (base+1<n)?deg[base+1]:0;
  int v2 = (base+2<n)?deg[base+2]:0;
  int v3 = (base+3<n)?deg[base+3]:0;
  int tsum = v0+v1+v2+v3;
  ls[t] = tsum; __syncthreads();
  for (int o=1;o<256;o<<=1){
    int x = (t>=o) ? ls[t-o] : 0;
    __syncthreads();
    ls[t] += x;
    __syncthreads();
  }
  int excl = ls[t]-tsum;
  if (t==255) bsum[b] = ls[255];
  if (base+0<n) rowptr[base+0]=excl;
  if (base+1<n) rowptr[base+1]=excl+v0;
  if (base+2<n) rowptr[base+2]=excl+v0+v1;
  if (base+3<n) rowptr[base+3]=excl+v0+v1+v2;
}

__global__ __launch_bounds__(64) void k_scan2(int* __restrict__ bsum, int nb,
                                              int* __restrict__ rowptr, int n){
  if (threadIdx.x==0){
    int run = 0;
    for (int b=0;b<nb;b++){ int x = bsum[b]; bsum[b] = run; run += x; }
    rowptr[n] = run;
  }
}

__global__ __launch_bounds__(256) void k_scan3(int* __restrict__ rowptr,
                                               const int* __restrict__ bsum,
                                               int* __restrict__ cursor, int n){
  int i = blockIdx.x*256 + threadIdx.x;
  if (i < n){
    int r = rowptr[i] + bsum[i>>10];
    rowptr[i] = r;
    cursor[i] = r;
  }
}

__global__ __launch_bounds__(256) void k_scatter(const int* __restrict__ dst,
                                                 int* __restrict__ cursor,
                                                 int* __restrict__ eidx, int E){
  int e = blockIdx.x*256 + threadIdx.x;
  if (e < E){
    int p = atomicAdd(&cursor[dst[e]], 1);
    eidx[p] = e;
  }
}

// ---------------- meta-graph edges (tiny, atomic version) ----------------
__global__ __launch_bounds__(256) void edge_meta(
    const int* __restrict__ src, const int* __restrict__ dst,
    const unsigned short* __restrict__ qm, const unsigned short* __restrict__ kfm,
    const unsigned short* __restrict__ vm,
    const float* __restrict__ base, unsigned short* __restrict__ mef,
    float* __restrict__ z, float* __restrict__ agg, int E)
{
  int e = blockIdx.x*4 + (threadIdx.x>>6);
  if (e >= E) return;
  int lane = threadIdx.x & 63;
  int s = src[e], d = dst[e];
  const float* be2 = base+152; const float* be1 = base+16; const float* bn1 = base+8;
  size_t so=(size_t)s*DD, dq=(size_t)d*DD, eo=(size_t)e*DD;
  float ke0 = b2f(kfm[so+lane])    * be2[lane];
  float ke1 = b2f(kfm[so+64+lane]) * be2[64+lane];
  mef[eo+lane]=f2b(ke0); mef[eo+64+lane]=f2b(ke1);
  float p0 = b2f(qm[dq+lane])*ke0, p1 = b2f(qm[dq+64+lane])*ke1;
#pragma unroll
  for (int m=1;m<16;m<<=1){ p0 += __shfl_xor(p0,m,64); p1 += __shfl_xor(p1,m,64); }
  int h0 = lane>>4, h1 = h0+4;
  float s0 = p0*0.25f + be1[h0] + bn1[h0];
  float s1 = p1*0.25f + be1[h1] + bn1[h1];
  float e0 = __expf(s0), e1 = __expf(s1);
  if ((lane&15)==0){ atomicAdd(&z[(size_t)d*HH+h0], e0); atomicAdd(&z[(size_t)d*HH+h1], e1); }
  atomicAdd(&agg[dq+lane],    e0*b2f(vm[so+lane]));
  atomicAdd(&agg[dq+64+lane], e1*b2f(vm[so+64+lane]));
}

// ---------------- big-graph: fused scores+agg, unroll-2 pipelined ----------------
// One wave per dst. Lane holds elems (2*lane,2*lane+1); head = lane>>3.
__global__ __launch_bounds__(256) void edge_fused(
    const int* __restrict__ rowptr, const int* __restrict__ eidx,
    const int* __restrict__ src, const int* __restrict__ meid,
    const int* __restrict__ mnid,
    const unsigned short* __restrict__ q, const unsigned short* __restrict__ kf,
    const unsigned short* __restrict__ v,
    const unsigned short* __restrict__ p2me, const unsigned short* __restrict__ p1me,
    const float* __restrict__ p1mn, const float* __restrict__ base,
    float* __restrict__ z, float* __restrict__ agg, int N)
{
  int d = blockIdx.x*4 + (threadIdx.x>>6);
  if (d >= N) return;
  int lane = threadIdx.x & 63;
  int c2 = lane*2;
  int h = lane>>3;
  size_t dq = (size_t)d*DD;
  const float* be2 = base+152; const float* be1 = base+16; const float* bn1 = base+8;
  us2 qp = *(const us2*)(q + dq + c2);
  float qa = b2f(qp.x), qb = b2f(qp.y);
  float w2a = be2[c2], w2b = be2[c2+1];
  int mn = mnid[d];
  float bias = be1[h] + bn1[h] + p1mn[(size_t)mn*HH + h];
  float zh = 0.f, a0 = 0.f, a1 = 0.f;
  int i0 = rowptr[d], i1 = rowptr[d+1];
  int i = i0;
  for (; i+2 <= i1; i += 2){
    int e0 = eidx[i], e1 = eidx[i+1];
    int s0 = src[e0], me0 = meid[e0];
    int s1 = src[e1], me1 = meid[e1];
    size_t so0=(size_t)s0*DD, mo0=(size_t)me0*DD;
    size_t so1=(size_t)s1*DD, mo1=(size_t)me1*DD;
    // issue all 8 gathers before any use (2x memory-level parallelism)
    us2 kp0 = *(const us2*)(kf + so0 + c2);
    us2 pp0 = *(const us2*)(p2me + mo0 + c2);
    us2 vp0 = *(const us2*)(v + so0 + c2);
    float pm0 = b2f(p1me[(size_t)me0*HH + h]);
    us2 kp1 = *(const us2*)(kf + so1 + c2);
    us2 pp1 = *(const us2*)(p2me + mo1 + c2);
    us2 vp1 = *(const us2*)(v + so1 + c2);
    float pm1 = b2f(p1me[(size_t)me1*HH + h]);
    float pA = qa*(b2f(kp0.x)*(w2a + b2f(pp0.x))) + qb*(b2f(kp0.y)*(w2b + b2f(pp0.y)));
    float pB = qa*(b2f(kp1.x)*(w2a + b2f(pp1.x))) + qb*(b2f(kp1.y)*(w2b + b2f(pp1.y)));
    pA += __shfl_xor(pA,1,64); pB += __shfl_xor(pB,1,64);
    pA += __shfl_xor(pA,2,64); pB += __shfl_xor(pB,2,64);
    pA += __shfl_xor(pA,4,64); pB += __shfl_xor(pB,4,64);
    float ex0 = __expf(pA*0.25f + bias + pm0);
    float ex1 = __expf(pB*0.25f + bias + pm1);
    zh += ex0 + ex1;
    a0 += ex0*b2f(vp0.x) + ex1*b2f(vp1.x);
    a1 += ex0*b2f(vp0.y) + ex1*b2f(vp1.y);
  }
  if (i < i1){
    int e = eidx[i];
    int s = src[e], me = meid[e];
    size_t so = (size_t)s*DD, mo = (size_t)me*DD;
    us2 kp = *(const us2*)(kf + so + c2);
    us2 pp = *(const us2*)(p2me + mo + c2);
    us2 vp = *(const us2*)(v + so + c2);
    float pm = b2f(p1me[(size_t)me*HH + h]);
    float p = qa*(b2f(kp.x)*(w2a + b2f(pp.x))) + qb*(b2f(kp.y)*(w2b + b2f(pp.y)));
    p += __shfl_xor(p,1,64); p += __shfl_xor(p,2,64); p += __shfl_xor(p,4,64);
    float ex = __expf(p*0.25f + bias + pm);
    zh += ex;
    a0 += ex*b2f(vp.x);
    a1 += ex*b2f(vp.y);
  }
  if ((lane&7)==0) z[(size_t)d*HH + h] = zh;
  *(float2*)(agg + dq + c2) = make_float2(a0, a1);
}

template<bool XB, bool PB>
__global__ __launch_bounds__(128) void learner(
    const void* __restrict__ X, const void* __restrict__ u,
    const void* __restrict__ W2, const void* __restrict__ W1,
    void* __restrict__ p2, void* __restrict__ p1, const int* __restrict__ dflag)
{
  __shared__ float sX[128];
  __shared__ float st[16];
  __shared__ float sw[16];
  const bool wf32 = (*dflag) != 0;
  const int m = blockIdx.x, t = threadIdx.x;
  if (XB) sX[t] = b2f(((const unsigned short*)X)[(size_t)m*DD + t]);
  else    sX[t] = ((const float*)X)[(size_t)m*DD + t];
  __syncthreads();
  int l = t>>3, j = t&7;
  float part = 0.f;
  for (int d=j*16; d<j*16+16; d++) part += sX[d]*gld(u, l*128+d, wf32);
  part += __shfl_xor(part,1,64); part += __shfl_xor(part,2,64); part += __shfl_xor(part,4,64);
  if (j==0) st[l] = part * 0.08838834764831845f;
  __syncthreads();
  float mx=-1e30f;
  for (int i=0;i<16;i++) mx = fmaxf(mx, st[i]);
  float ssum=0.f;
  for (int i=0;i<16;i++) ssum += __expf(st[i]-mx);
  float inv = 1.f/ssum;
  if (t<16) sw[t] = __expf(st[t]-mx)*inv;
  __syncthreads();
  float a=0.f;
  for (int i=0;i<16;i++) a += sw[i]*gld(W2, i*128+t, wf32);
  if (PB) ((unsigned short*)p2)[(size_t)m*DD+t] = f2b(a);
  else    ((float*)p2)[(size_t)m*DD+t] = a;
  if (t<8){
    float bb=0.f;
    for (int i=0;i<16;i++) bb += sw[i]*gld(W1, i*8+t, wf32);
    if (PB) ((unsigned short*)p1)[(size_t)m*HH+t] = f2b(bb);
    else    ((float*)p1)[(size_t)m*HH+t] = bb;
  }
}

__global__ __launch_bounds__(256) void resadd(float* __restrict__ a, const float* __restrict__ b, int n){
  int i = blockIdx.x*256 + threadIdx.x;
  if (i < n) a[i] += b[i];
}

__global__ __launch_bounds__(256) void readout(
    const int* __restrict__ tgt, const int* __restrict__ mnid,
    const unsigned short* __restrict__ featb, const float* __restrict__ p1mn,
    const float* __restrict__ base, float* __restrict__ acc,
    void* __restrict__ out, int last, float invNB, int BT,
    const int* __restrict__ dflag)
{
  int t = blockIdx.x*256 + threadIdx.x;
  if (t >= BT) return;
  int idx = tgt[t]; int mn = mnid[idx];
  float logit = 0.f;
  for (int h=0;h<8;h++){
    float tw = base[h] + p1mn[(size_t)mn*HH + h];
    float srow = 0.f;
    for (int k=0;k<16;k++) srow += b2f(featb[(size_t)idx*DD + h*16 + k]);
    logit += tw*srow;
  }
  if (!last) acc[t] = logit;
  else {
    float r = (acc[t] + logit) * invNB;
    if ((*dflag) != 0) ((float*)out)[t] = r;
    else ((__hip_bfloat16*)out)[t] = __float2bfloat16(r);
  }
}

extern "C" void kernel_launch(void* const* d_in, const int* in_sizes, int n_in,
                              void* d_out, int out_size, void* d_ws, size_t ws_size,
                              hipStream_t stream) {
  const void* emb   = d_in[0];
  const void* u     = d_in[1];
  const void* W2lat = d_in[2];
  const void* W1lat = d_in[3];
  WPtrs wptrs;
  for (int i=0;i<8;i++) wptrs.p[i] = d_in[4+i];
  const int* node_vals      = (const int*)d_in[12];
  const int* meta_node_vals = (const int*)d_in[13];
  const int* src            = (const int*)d_in[14];
  const int* dst            = (const int*)d_in[15];
  const int* meta_src       = (const int*)d_in[16];
  const int* meta_dst       = (const int*)d_in[17];
  const int* meta_node_id   = (const int*)d_in[18];
  const int* meta_edge_id   = (const int*)d_in[19];
  const int* target_idx     = (const int*)d_in[20];
  const int* static_vals    = (const int*)d_in[21];
  const int* static_src     = (const int*)d_in[22];
  const int* static_dst     = (const int*)d_in[23];

  const int N  = in_sizes[12];
  const int MN = in_sizes[13];
  const int E  = in_sizes[14];
  const int ME = in_sizes[16];
  const int BT = in_sizes[20];
  const int NSRC = in_sizes[22];
  const int NB = in_sizes[8] / (DD*DD);

  float* ws = (float*)d_ws;
  size_t off = 0;
  auto allocf = [&](size_t n){ float* p = ws + off; off += n; return p; };
  auto allocb = [&](size_t n){ unsigned short* p = (unsigned short*)(ws + off); off += (n+1)/2; return p; };
  auto alloci = [&](size_t n){ int* p = (int*)(ws + off); off += n; return p; };
  int*            dflag = (int*)ws; off += 4;
  unsigned short* feat  = allocb((size_t)N*DD);
  unsigned short* q     = allocb((size_t)N*DD);
  unsigned short* kf    = allocb((size_t)N*DD);
  unsigned short* v     = allocb((size_t)N*DD);
  float*          agg   = allocf((size_t)N*DD);
  float*          z     = allocf((size_t)N*HH);
  float*          meta_feat= allocf((size_t)MN*DD);
  float*          agg_m = allocf((size_t)MN*DD);  // z_m contiguous follows
  float*          z_m   = allocf((size_t)MN*HH);
  unsigned short* q_m   = allocb((size_t)MN*DD);
  unsigned short* kf_m  = allocb((size_t)MN*DD);
  unsigned short* v_m   = allocb((size_t)MN*DD);
  float*          meta_out = allocf((size_t)MN*DD);
  unsigned short* mef   = allocb((size_t)ME*DD);
  float*          p2mn  = allocf((size_t)MN*DD);
  float*          p1mn  = allocf((size_t)MN*HH);
  unsigned short* p2me  = allocb((size_t)ME*DD);
  unsigned short* p1me  = allocb((size_t)ME*HH);
  float*          base  = allocf(280);
  float*          acc   = allocf((size_t)BT);
  unsigned short* wstage= allocb((size_t)8*DD*DD);
  int*            rowptr= alloci((size_t)N+1);
  int*            cursor= alloci((size_t)N);
  int*            deg   = alloci((size_t)N);
  int*            eidx  = alloci((size_t)E);
  const int nb_scan = (N + 1023)/1024;
  int*            bsum  = alloci((size_t)nb_scan);
  (void)ws_size; (void)n_in; (void)out_size;

  const float* base_n2 = base + 24;

  k_detect<<<1,64,0,stream>>>((const unsigned short*)emb, dflag);
  k_static<<<1,256,0,stream>>>(emb, static_vals, static_src, static_dst,
                               u, W2lat, W1lat, base, NSRC, dflag);
  gather_rows<true ><<<(N*16+255)/256,256,0,stream>>>(emb, node_vals, feat, N, dflag);
  gather_rows<false><<<(MN*16+255)/256,256,0,stream>>>(emb, meta_node_vals, meta_feat, MN, dflag);

  // ---- CSR build (by dst), once per call ----
  zeroi<<<(N+255)/256,256,0,stream>>>(deg, N);
  k_hist<<<(E+255)/256,256,0,stream>>>(dst, deg, E);
  k_scan1<<<nb_scan,256,0,stream>>>(deg, rowptr, bsum, N);
  k_scan2<<<1,64,0,stream>>>(bsum, nb_scan, rowptr, N);
  k_scan3<<<(N+255)/256,256,0,stream>>>(rowptr, bsum, cursor, N);
  k_scatter<<<(E+255)/256,256,0,stream>>>(dst, cursor, eidx, E);

  const int gm = (MN+63)/64;
  const int gN = (N+63)/64;
  const long nz_meta = ((long)MN*DD + (long)MN*HH)/4;
  const float invNB = 1.0f/(float)NB;

  for (int b=0;b<NB;b++){
    const size_t bo = (size_t)b*DD*DD;
    w_repack8<<<512,256,0,stream>>>(wptrs, wstage, bo, dflag);
    const unsigned short* wq_m = wstage + 0*DD*DD;
    const unsigned short* wk_m = wstage + 1*DD*DD;
    const unsigned short* wv_m = wstage + 2*DD*DD;
    const unsigned short* wo_m = wstage + 3*DD*DD;
    const unsigned short* wqb  = wstage + 4*DD*DD;
    const unsigned short* wkb  = wstage + 5*DD*DD;
    const unsigned short* wvb  = wstage + 6*DD*DD;
    const unsigned short* wob  = wstage + 7*DD*DD;

    // ---- meta conv (broadcast base params) ----
    gemm_qkv<EPI_SCALE_CONST,false><<<gm,256,0,stream>>>(meta_feat, wq_m, wk_m, wv_m,
        q_m, kf_m, v_m, MN, base_n2, nullptr, nullptr);
    zerof<<<(int)((nz_meta+255)/256),256,0,stream>>>(agg_m, nz_meta);
    edge_meta<<<(ME+3)/4,256,0,stream>>>(meta_src, meta_dst, q_m, kf_m, v_m,
        base, mef, z_m, agg_m, ME);
    gemm128m<EPI_RELU,true,false,false><<<gm,256,0,stream>>>(agg_m, wo_m, meta_out, MN,
        z_m, nullptr, nullptr, nullptr, nullptr);

    // ---- meta learners (pre-residual conv outputs) ----
    learner<false,false><<<MN,128,0,stream>>>(meta_out, u, W2lat, W1lat, p2mn, p1mn, dflag);
    learner<true ,true ><<<ME,128,0,stream>>>(mef,      u, W2lat, W1lat, p2me, p1me, dflag);
    resadd<<<(MN*DD+255)/256,256,0,stream>>>(meta_feat, meta_out, MN*DD);

    // ---- big conv ----
    gemm_qkv<EPI_SCALE_GATHER,true><<<gN,256,0,stream>>>(feat, wqb, wkb, wvb,
        q, kf, v, N, base_n2, p2mn, meta_node_id);
    edge_fused<<<(N+3)/4,256,0,stream>>>(rowptr, eidx, src, meta_edge_id,
        meta_node_id, q, kf, v, p2me, p1me, p1mn, base, z, agg, N);
    gemm128m<EPI_RELU_RES,true,false,true><<<gN,256,0,stream>>>(agg, wob, feat, N,
        z, nullptr, nullptr, nullptr, feat);

    // ---- readout ----
    readout<<<(BT+255)/256,256,0,stream>>>(target_idx, meta_node_id, feat, p1mn,
        base, acc, d_out, (b==NB-1) ? 1 : 0, invNB, BT, dflag);
  }
}